// Round 7
// baseline (717.942 us; speedup 1.0000x reference)
//
#include <hip/hip_runtime.h>
#include <math.h>

#define N_NODES   50000
#define N_EDGES   800000
#define NUM_GRAPHS 64
#define FDIM      64
#define HDIM      64
#define NLAYERS   3
#define NCLASSES  16
#define EPS       1e-5f

#define SCAN_CHUNK 1024
#define NCHUNKS ((N_NODES + SCAN_CHUNK - 1) / SCAN_CHUNK)   // 49

typedef unsigned short u16;
typedef unsigned int   u32;
typedef __attribute__((ext_vector_type(8))) short short8;   // 8 bf16 (4 VGPRs)
typedef __attribute__((ext_vector_type(4))) float floatx4;  // MFMA accum

// WkS layout per layer (u16 bf16 bits, fragment-ordered):
//   [26 kchunk][3 split][64 n][32 k]  -> 159744 u16 per layer
#define WKS_LAYER 159744

// ---------------------------------------------------------------------------
// exact 3-way truncation split of fp32 into bf16 terms: f = h + m + l + eps,
// |eps| <= ~2^-24 |f|.  (h,m,l returned as bf16 bit patterns)
__device__ inline void split1(float f, u16& h, u16& m, u16& l) {
    u32 b  = __float_as_uint(f);
    u32 hb = b & 0xFFFF0000u;
    float r = f - __uint_as_float(hb);
    u32 mb = __float_as_uint(r) & 0xFFFF0000u;
    float r2 = r - __uint_as_float(mb);
    u32 lb = __float_as_uint(r2) & 0xFFFF0000u;
    h = (u16)(hb >> 16); m = (u16)(mb >> 16); l = (u16)(lb >> 16);
}

// ---------------------------------------------------------------------------
// Weight folding Wk = (lin_w @ post_w), written as 3-way bf16 split in
// MFMA B-fragment order; bc = lin_b + lin_w@post_b; zero-inits cnt/logsum.
__global__ __launch_bounds__(256) void k_comb(const float* __restrict__ post_w,
                                              const float* __restrict__ lin_w,
                                              const float* __restrict__ post_b,
                                              const float* __restrict__ lin_b,
                                              u16* __restrict__ WkS,
                                              float* __restrict__ bcv,
                                              int* __restrict__ cnt,
                                              float* __restrict__ logsum) {
    int b = blockIdx.x, t = threadIdx.x;
    int zi = b * 256 + t;
    if (zi < N_NODES) cnt[zi] = 0;
    if (zi == 0) *logsum = 0.f;

    if (b < 624) {
        int c  = t & 63;
        int kl = t >> 6;
        int l  = b / 208;
        int k  = (b % 208) * 4 + kl;
        const float* lw = lin_w + (size_t)l * 4096 + c * 64;
        const float* pw = post_w + (size_t)l * 53248 + k;
        float acc = 0.f;
        #pragma unroll 8
        for (int j = 0; j < 64; ++j)
            acc += lw[j] * pw[(size_t)j * 832];
        u16 h, m, lo;
        split1(acc, h, m, lo);
        size_t base = (size_t)l * WKS_LAYER + (size_t)(k >> 5) * 6144 + c * 32 + (k & 31);
        WkS[base]        = h;
        WkS[base + 2048] = m;
        WkS[base + 4096] = lo;
    } else if (t < 192) {
        int l = t >> 6, c = t & 63;
        float acc = lin_b[l * 64 + c];
        for (int j = 0; j < 64; ++j)
            acc += lin_w[(size_t)l * 4096 + c * 64 + j] * post_b[l * 64 + j];
        bcv[l * 64 + c] = acc;
    }
}

// ---------------------------------------------------------------------------
// CSR build: degree histogram
__global__ void k_count(const int* __restrict__ dst, int* __restrict__ cnt) {
    int e = blockIdx.x * 256 + threadIdx.x;
    if (e < N_EDGES) atomicAdd(&cnt[dst[e]], 1);
}

__global__ void k_chunk_sums(const int* __restrict__ cnt, int* __restrict__ bsum,
                             float* __restrict__ logsum) {
    __shared__ int   ired[256];
    __shared__ float lred[256];
    int b = blockIdx.x, t = threadIdx.x;
    int base = b * SCAN_CHUNK;
    int s = 0; float ls = 0.f;
    for (int i = t; i < SCAN_CHUNK; i += 256) {
        int idx = base + i;
        if (idx < N_NODES) {
            int v = cnt[idx];
            s += v;
            ls += logf((float)v + 1.0f);
        }
    }
    ired[t] = s; lred[t] = ls;
    __syncthreads();
    for (int off = 128; off > 0; off >>= 1) {
        if (t < off) { ired[t] += ired[t + off]; lred[t] += lred[t + off]; }
        __syncthreads();
    }
    if (t == 0) { bsum[b] = ired[0]; atomicAdd(logsum, lred[0]); }
}

__global__ void k_scan_top(const int* __restrict__ bsum, int* __restrict__ boff,
                           int* __restrict__ row_start) {
    if (threadIdx.x == 0) {
        int acc = 0;
        for (int i = 0; i < NCHUNKS; ++i) { boff[i] = acc; acc += bsum[i]; }
        row_start[N_NODES] = acc;
    }
}

__global__ void k_scan_chunks(const int* __restrict__ cnt, const int* __restrict__ boff,
                              int* __restrict__ row_start, int* __restrict__ cursor) {
    __shared__ int tsum[256];
    int b = blockIdx.x, t = threadIdx.x;
    int base = b * SCAN_CHUNK + t * 4;
    int v[4]; int s = 0;
    #pragma unroll
    for (int i = 0; i < 4; ++i) {
        int idx = base + i;
        v[i] = (idx < N_NODES) ? cnt[idx] : 0;
        s += v[i];
    }
    tsum[t] = s;
    __syncthreads();
    for (int off = 1; off < 256; off <<= 1) {
        int val = (t >= off) ? tsum[t - off] : 0;
        __syncthreads();
        tsum[t] += val;
        __syncthreads();
    }
    int excl = boff[b] + tsum[t] - s;
    #pragma unroll
    for (int i = 0; i < 4; ++i) {
        int idx = base + i;
        if (idx < N_NODES) { row_start[idx] = excl; cursor[idx] = excl; }
        excl += v[i];
    }
}

__global__ void k_scatter(const int* __restrict__ src, const int* __restrict__ dst,
                          int* __restrict__ cursor, int* __restrict__ csr_src) {
    int e = blockIdx.x * 256 + threadIdx.x;
    if (e < N_EDGES) {
        int d = dst[e];
        int slot = atomicAdd(&cursor[d], 1);
        csr_src[slot] = src[e];
    }
}

// per-node degree scalers; block 0 also zero-inits pooling accumulators
__global__ void k_scal(const int* __restrict__ cnt, const float* __restrict__ logsum,
                       float* __restrict__ inv_deg, float* __restrict__ ampv,
                       float* __restrict__ attv, float* __restrict__ g_sum,
                       int* __restrict__ g_cnt) {
    int n = blockIdx.x * 256 + threadIdx.x;
    if (blockIdx.x == 0) {
        for (int i = threadIdx.x; i < 4096; i += 256) g_sum[i] = 0.f;
        if (threadIdx.x < 64) g_cnt[threadIdx.x] = 0;
    }
    if (n < N_NODES) {
        float avg = logsum[0] / (float)N_NODES;
        float degf = fmaxf((float)cnt[n], 1.0f);
        inv_deg[n] = 1.0f / degf;
        float ld = logf(degf + 1.0f);
        ampv[n] = ld / avg;
        attv[n] = avg / ld;
    }
}

// ---------------------------------------------------------------------------
// p = x @ Wi^T + pre_b ; q = x @ Wj^T  (unchanged, passing r6 version)
__global__ __launch_bounds__(256) void k_pre(const float* __restrict__ x,
                                             const float* __restrict__ pre_w,
                                             const float* __restrict__ pre_b,
                                             float* __restrict__ p,
                                             float* __restrict__ q) {
    __shared__ float At[64][68];
    __shared__ float Wt[128][68];
    int t = threadIdx.x;
    int c4 = (t & 15) * 4;
    int r4 = (t >> 4) * 4;
    int rowBase = blockIdx.x * 64;
    int srow = t >> 2, skq = t & 3;

    #pragma unroll
    for (int pass = 0; pass < 4; ++pass) {
        int kk = (pass * 4 + skq) * 4;
        int row = rowBase + srow;
        float4 v = make_float4(0.f, 0.f, 0.f, 0.f);
        if (row < N_NODES) v = *(const float4*)&x[(size_t)row * 64 + kk];
        At[kk + 0][srow] = v.x;
        At[kk + 1][srow] = v.y;
        At[kk + 2][srow] = v.z;
        At[kk + 3][srow] = v.w;
    }
    for (int idx4 = t; idx4 < 2048; idx4 += 256) {
        int c = idx4 & 63, kq = idx4 >> 6;
        float4 v = *(const float4*)&pre_w[(size_t)c * 128 + kq * 4];
        Wt[kq * 4 + 0][c] = v.x;
        Wt[kq * 4 + 1][c] = v.y;
        Wt[kq * 4 + 2][c] = v.z;
        Wt[kq * 4 + 3][c] = v.w;
    }
    __syncthreads();

    float accp[4][4] = {{0}}, accq[4][4] = {{0}};
    #pragma unroll 4
    for (int kk = 0; kk < 64; ++kk) {
        float4 a  = *(const float4*)&At[kk][r4];
        float4 wp = *(const float4*)&Wt[kk][c4];
        float4 wq = *(const float4*)&Wt[64 + kk][c4];
        float av[4]  = {a.x, a.y, a.z, a.w};
        float wpv[4] = {wp.x, wp.y, wp.z, wp.w};
        float wqv[4] = {wq.x, wq.y, wq.z, wq.w};
        #pragma unroll
        for (int i = 0; i < 4; ++i)
            #pragma unroll
            for (int j = 0; j < 4; ++j) {
                accp[i][j] += av[i] * wpv[j];
                accq[i][j] += av[i] * wqv[j];
            }
    }
    float pb[4];
    #pragma unroll
    for (int j = 0; j < 4; ++j) pb[j] = pre_b[c4 + j];
    #pragma unroll
    for (int i = 0; i < 4; ++i) {
        int row = rowBase + r4 + i;
        if (row < N_NODES) {
            float4 vp = make_float4(accp[i][0] + pb[0], accp[i][1] + pb[1],
                                    accp[i][2] + pb[2], accp[i][3] + pb[3]);
            float4 vq = make_float4(accq[i][0], accq[i][1], accq[i][2], accq[i][3]);
            *(float4*)&p[row * 64 + c4] = vp;
            *(float4*)&q[row * 64 + c4] = vq;
        }
    }
}

// ---------------------------------------------------------------------------
// Aggregation (unchanged, passing r6 version)
__global__ __launch_bounds__(256) void k_aggr(const float* __restrict__ p,
                                              const float* __restrict__ q,
                                              const int* __restrict__ row_start,
                                              const int* __restrict__ csr_src,
                                              const float* __restrict__ inv_deg,
                                              float* __restrict__ aggr) {
    int wid  = (blockIdx.x * 256 + threadIdx.x) >> 6;
    int lane = threadIdx.x & 63;
    if (wid >= N_NODES) return;
    int n = wid;
    int beg = row_start[n], end = row_start[n + 1];
    float sum = 0.f, sq = 0.f;
    float mn = INFINITY, mx = -INFINITY;
    int e = beg;
    for (; e + 7 < end; e += 8) {
        float qv[8];
        #pragma unroll
        for (int u = 0; u < 8; ++u) {
            int s = csr_src[e + u];
            qv[u] = q[(size_t)s * 64 + lane];
        }
        #pragma unroll
        for (int u = 0; u < 8; ++u) {
            float m = qv[u];
            sum += m; sq += m * m;
            mn = fminf(mn, m); mx = fmaxf(mx, m);
        }
    }
    for (; e + 3 < end; e += 4) {
        float qv[4];
        #pragma unroll
        for (int u = 0; u < 4; ++u) {
            int s = csr_src[e + u];
            qv[u] = q[(size_t)s * 64 + lane];
        }
        #pragma unroll
        for (int u = 0; u < 4; ++u) {
            float m = qv[u];
            sum += m; sq += m * m;
            mn = fminf(mn, m); mx = fmaxf(mx, m);
        }
    }
    for (; e < end; ++e) {
        int s = csr_src[e];
        float m = q[(size_t)s * 64 + lane];
        sum += m; sq += m * m;
        mn = fminf(mn, m); mx = fmaxf(mx, m);
    }
    float* a = aggr + (size_t)n * 256;
    if (end <= beg) {
        a[lane]       = 0.f;
        a[64 + lane]  = 0.f;
        a[128 + lane] = 0.f;
        a[192 + lane] = sqrtf(EPS);
    } else {
        float pv = p[n * 64 + lane];
        float id = inv_deg[n];
        float meanq = sum * id;
        float var = fmaxf(sq * id - meanq * meanq, 0.f);
        a[lane]       = pv + meanq;
        a[64 + lane]  = pv + mn;
        a[128 + lane] = pv + mx;
        a[192 + lane] = sqrtf(var + EPS);
    }
}

// ---------------------------------------------------------------------------
// MFMA k_post: x_next = relu( A @ Wk + bc ), A=[x|aggr|amp*aggr|att*aggr] K=832
// 3-way exact bf16 split, 6 MFMA products per tile (error ~2^-24).
// No LDS, no barriers: A-frags = 32B row-major global reads split in-register;
// B-frags = coalesced reads of fragment-ordered pre-split weights (L1/L2-hot).
// Wave w owns output rows [16w,16w+16); 4 n-tiles of 16; K = 26 chunks of 32.
__global__ __launch_bounds__(256) void k_post(const float* __restrict__ x,
                                              const float* __restrict__ aggr,
                                              const float* __restrict__ ampv,
                                              const float* __restrict__ attv,
                                              const u16* __restrict__ WkS,
                                              const float* __restrict__ bc,
                                              float* __restrict__ xout) {
    int t = threadIdx.x;
    int w = t >> 6;
    int lane = t & 63;
    int m = lane & 15;          // A row within wave's 16-row tile
    int qh = lane >> 4;         // k-eighth selector (0..3)
    int rowBase = blockIdx.x * 64;

    int myrow = rowBase + 16 * w + m;
    bool vr = myrow < N_NODES;
    float ampR = vr ? ampv[myrow] : 0.f;
    float attR = vr ? attv[myrow] : 0.f;
    const float* xrow = x + (size_t)(vr ? myrow : 0) * 64;
    const float* arow = aggr + (size_t)(vr ? myrow : 0) * 256;

    // B-fragment per-lane offset within a [64 n][32 k] u16 tile
    int bo = (lane & 15) * 32 + qh * 8;

    floatx4 acc[4] = {};

    float fc[8], fn[8];

    auto loadA = [&](int ch, float* f) {
        if (!vr) {
            #pragma unroll
            for (int i = 0; i < 8; ++i) f[i] = 0.f;
            return;
        }
        int k0 = ch * 32 + qh * 8;
        const float* sp;
        float sc = 1.f;
        if (k0 < 64)       sp = xrow + k0;
        else if (k0 < 320) sp = arow + (k0 - 64);
        else if (k0 < 576) { sp = arow + (k0 - 320); sc = ampR; }
        else               { sp = arow + (k0 - 576); sc = attR; }
        float4 u0 = *(const float4*)sp;
        float4 u1 = *(const float4*)(sp + 4);
        f[0] = u0.x * sc; f[1] = u0.y * sc; f[2] = u0.z * sc; f[3] = u0.w * sc;
        f[4] = u1.x * sc; f[5] = u1.y * sc; f[6] = u1.z * sc; f[7] = u1.w * sc;
    };

    loadA(0, fc);

    for (int ch = 0; ch < 26; ++ch) {
        if (ch < 25) loadA(ch + 1, fn);

        // in-register exact 3-way split of the 8 A elements
        union { u32 u[4]; short8 s; } AH, AM, AL;
        #pragma unroll
        for (int i = 0; i < 4; ++i) {
            float f0 = fc[2 * i], f1 = fc[2 * i + 1];
            u32 b0 = __float_as_uint(f0), b1 = __float_as_uint(f1);
            u32 h0 = b0 & 0xFFFF0000u,  h1 = b1 & 0xFFFF0000u;
            float r0 = f0 - __uint_as_float(h0);
            float r1 = f1 - __uint_as_float(h1);
            u32 m0 = __float_as_uint(r0) & 0xFFFF0000u;
            u32 m1 = __float_as_uint(r1) & 0xFFFF0000u;
            float s0 = r0 - __uint_as_float(m0);
            float s1 = r1 - __uint_as_float(m1);
            u32 l0 = __float_as_uint(s0) & 0xFFFF0000u;
            u32 l1 = __float_as_uint(s1) & 0xFFFF0000u;
            AH.u[i] = (h0 >> 16) | h1;
            AM.u[i] = (m0 >> 16) | m1;
            AL.u[i] = (l0 >> 16) | l1;
        }

        const u16* Bb = WkS + (size_t)ch * 6144;
        #pragma unroll
        for (int nt = 0; nt < 4; ++nt) {
            short8 bH = *(const short8*)(Bb + nt * 512 + bo);
            short8 bM = *(const short8*)(Bb + 2048 + nt * 512 + bo);
            short8 bL = *(const short8*)(Bb + 4096 + nt * 512 + bo);
            acc[nt] = __builtin_amdgcn_mfma_f32_16x16x32_bf16(AH.s, bH, acc[nt], 0, 0, 0);
            acc[nt] = __builtin_amdgcn_mfma_f32_16x16x32_bf16(AH.s, bM, acc[nt], 0, 0, 0);
            acc[nt] = __builtin_amdgcn_mfma_f32_16x16x32_bf16(AM.s, bH, acc[nt], 0, 0, 0);
            acc[nt] = __builtin_amdgcn_mfma_f32_16x16x32_bf16(AH.s, bL, acc[nt], 0, 0, 0);
            acc[nt] = __builtin_amdgcn_mfma_f32_16x16x32_bf16(AM.s, bM, acc[nt], 0, 0, 0);
            acc[nt] = __builtin_amdgcn_mfma_f32_16x16x32_bf16(AL.s, bH, acc[nt], 0, 0, 0);
        }

        #pragma unroll
        for (int i = 0; i < 8; ++i) fc[i] = fn[i];
    }

    // epilogue: C/D layout col = lane&15, row = (lane>>4)*4 + reg
    int col = lane & 15;
    #pragma unroll
    for (int nt = 0; nt < 4; ++nt) {
        float bias = bc[nt * 16 + col];
        #pragma unroll
        for (int reg = 0; reg < 4; ++reg) {
            int grow = rowBase + 16 * w + qh * 4 + reg;
            if (grow < N_NODES) {
                xout[(size_t)grow * 64 + nt * 16 + col] =
                    fmaxf(acc[nt][reg] + bias, 0.f);
            }
        }
    }
}

// ---------------------------------------------------------------------------
__global__ __launch_bounds__(256) void k_pool(const float* __restrict__ x,
                                              const int* __restrict__ batch,
                                              float* __restrict__ g_sum,
                                              int* __restrict__ g_cnt) {
    int lane = threadIdx.x & 63;
    int wave = blockIdx.x * 4 + (threadIdx.x >> 6);
    const int NPW = 128;
    int beg = wave * NPW;
    if (beg >= N_NODES) return;
    int end = min(beg + NPW, N_NODES);
    float acc = 0.f;
    int cur = batch[beg];
    int c = 0;
    for (int n = beg; n < end; ++n) {
        int b = batch[n];
        if (b != cur) {
            atomicAdd(&g_sum[cur * 64 + lane], acc);
            if (lane == 0) atomicAdd(&g_cnt[cur], c);
            acc = 0.f; c = 0; cur = b;
        }
        acc += x[n * 64 + lane];
        ++c;
    }
    atomicAdd(&g_sum[cur * 64 + lane], acc);
    if (lane == 0) atomicAdd(&g_cnt[cur], c);
}

__global__ __launch_bounds__(256) void k_mlp(const float* __restrict__ g_sum,
                                             const int* __restrict__ g_cnt,
                                             const float* __restrict__ w1,
                                             const float* __restrict__ b1,
                                             const float* __restrict__ w2,
                                             const float* __restrict__ b2,
                                             float* __restrict__ out) {
    __shared__ float g[64][64];
    __shared__ float h[64][64];
    __shared__ float wT[64][65];
    int t = threadIdx.x;
    for (int idx = t; idx < 4096; idx += 256) {
        int gi = idx >> 6, c = idx & 63;
        float cntf = fmaxf((float)g_cnt[gi], 1.f);
        g[gi][c] = g_sum[idx] / cntf;
    }
    for (int idx = t; idx < 4096; idx += 256) {
        int c = idx >> 6, k = idx & 63;
        wT[k][c] = w1[c * 64 + k];
    }
    __syncthreads();
    for (int idx = t; idx < 4096; idx += 256) {
        int gi = idx >> 6, c = idx & 63;
        float acc = b1[c];
        for (int k = 0; k < 64; ++k) acc += g[gi][k] * wT[k][c];
        h[gi][c] = fmaxf(acc, 0.f);
    }
    __syncthreads();
    for (int idx = t; idx < 64 * NCLASSES; idx += 256) {
        int gi = idx >> 4, c = idx & 15;
        float acc = b2[c];
        for (int k = 0; k < 64; ++k) acc += h[gi][k] * w2[c * 64 + k];
        out[gi * NCLASSES + c] = acc;
    }
}

// ---------------------------------------------------------------------------
extern "C" void kernel_launch(void* const* d_in, const int* in_sizes, int n_in,
                              void* d_out, int out_size, void* d_ws, size_t ws_size,
                              hipStream_t stream) {
    const float* x      = (const float*)d_in[0];
    const int*   ei     = (const int*)d_in[1];
    const int*   batch  = (const int*)d_in[2];
    const float* pre_w  = (const float*)d_in[3];
    const float* pre_b  = (const float*)d_in[4];
    const float* post_w = (const float*)d_in[5];
    const float* post_b = (const float*)d_in[6];
    const float* lin_w  = (const float*)d_in[7];
    const float* lin_b  = (const float*)d_in[8];
    const float* mlp_w1 = (const float*)d_in[9];
    const float* mlp_b1 = (const float*)d_in[10];
    const float* mlp_w2 = (const float*)d_in[11];
    const float* mlp_b2 = (const float*)d_in[12];

    const int* src = ei;
    const int* dst = ei + N_EDGES;

    char* base = (char*)d_ws;
    size_t off = 0;
    auto alloc = [&](size_t bytes) -> void* {
        void* ptr = base + off;
        off += (bytes + 255) & ~(size_t)255;
        return ptr;
    };
    int*   cnt       = (int*)alloc(N_NODES * 4);
    int*   row_start = (int*)alloc((N_NODES + 1) * 4);
    int*   cursor    = (int*)alloc(N_NODES * 4);
    int*   csr_src   = (int*)alloc(N_EDGES * 4);
    int*   bsum      = (int*)alloc(64 * 4);
    int*   boff      = (int*)alloc(64 * 4);
    float* logsum    = (float*)alloc(16);
    float* inv_deg   = (float*)alloc(N_NODES * 4);
    float* ampv      = (float*)alloc(N_NODES * 4);
    float* attv      = (float*)alloc(N_NODES * 4);
    float* p         = (float*)alloc((size_t)N_NODES * 64 * 4);
    float* q         = (float*)alloc((size_t)N_NODES * 64 * 4);
    float* aggr      = (float*)alloc((size_t)N_NODES * 256 * 4);
    float* xb0       = (float*)alloc((size_t)N_NODES * 64 * 4);
    float* xb1       = (float*)alloc((size_t)N_NODES * 64 * 4);
    float* g_sum     = (float*)alloc(64 * 64 * 4);
    int*   g_cnt     = (int*)alloc(64 * 4);
    u16*   WkS       = (u16*)alloc((size_t)3 * WKS_LAYER * 2);
    float* bcv       = (float*)alloc(3 * 64 * 4);

    // weight folding (pre-split bf16, frag-ordered) + workspace zero-init
    k_comb<<<625, 256, 0, stream>>>(post_w, lin_w, post_b, lin_b, WkS, bcv,
                                    cnt, logsum);

    k_count<<<(N_EDGES + 255) / 256, 256, 0, stream>>>(dst, cnt);
    k_chunk_sums<<<NCHUNKS, 256, 0, stream>>>(cnt, bsum, logsum);
    k_scan_top<<<1, 64, 0, stream>>>(bsum, boff, row_start);
    k_scan_chunks<<<NCHUNKS, 256, 0, stream>>>(cnt, boff, row_start, cursor);
    k_scatter<<<(N_EDGES + 255) / 256, 256, 0, stream>>>(src, dst, cursor, csr_src);
    k_scal<<<(N_NODES + 255) / 256, 256, 0, stream>>>(cnt, logsum, inv_deg,
                                                      ampv, attv, g_sum, g_cnt);

    const int GEMM_BLOCKS = (N_NODES + 63) / 64;   // 782
    const float* xin = x;
    float* bufs[3] = {xb0, xb1, xb0};
    for (int l = 0; l < NLAYERS; ++l) {
        k_pre<<<GEMM_BLOCKS, 256, 0, stream>>>(xin, pre_w + (size_t)l * 64 * 128,
                                               pre_b + l * 64, p, q);
        k_aggr<<<(N_NODES + 3) / 4, 256, 0, stream>>>(p, q, row_start, csr_src,
                                                      inv_deg, aggr);
        float* xo = bufs[l];
        k_post<<<GEMM_BLOCKS, 256, 0, stream>>>(xin, aggr, ampv, attv,
                                                WkS + (size_t)l * WKS_LAYER,
                                                bcv + l * 64, xo);
        xin = xo;
    }

    int pool_waves = (N_NODES + 127) / 128;
    k_pool<<<(pool_waves + 3) / 4, 256, 0, stream>>>(xin, batch, g_sum, g_cnt);
    k_mlp<<<1, 256, 0, stream>>>(g_sum, g_cnt, mlp_w1, mlp_b1, mlp_w2, mlp_b2,
                                 (float*)d_out);
}

// Round 8
// 702.501 us; speedup vs baseline: 1.0220x; 1.0220x over previous
//
#include <hip/hip_runtime.h>
#include <math.h>

#define N_NODES   50000
#define N_EDGES   800000
#define NUM_GRAPHS 64
#define FDIM      64
#define HDIM      64
#define NLAYERS   3
#define NCLASSES  16
#define EPS       1e-5f

#define SCAN_CHUNK 1024
#define NCHUNKS ((N_NODES + SCAN_CHUNK - 1) / SCAN_CHUNK)   // 49

typedef unsigned short u16;
typedef unsigned int   u32;
typedef __attribute__((ext_vector_type(8))) short short8;   // 8 bf16 (4 VGPRs)
typedef __attribute__((ext_vector_type(4))) float floatx4;  // MFMA accum

// WkS layout per layer (u16 bf16 bits):
//   [26 kchunk][3 split][4 ntile][16 n][32 k-swizzled] -> 159744 u16 per layer
// K-order: chunks 0-1 = x cols 0..63; then for aggr group j (j=0..7, 32 cols):
//   chunk 2+3j+0 = plain, +1 = amp, +2 = att.
// k position within a chunk row is swizzled: element (n16, kin=qh*8+jj) stored
// at n16*32 + ((qh + (n16>>1)) & 3)*8 + jj   (2-way LDS bank spread on read).
#define WKS_LAYER 159744

// ---------------------------------------------------------------------------
__device__ inline void split1(float f, u16& h, u16& m, u16& l) {
    u32 b  = __float_as_uint(f);
    u32 hb = b & 0xFFFF0000u;
    float r = f - __uint_as_float(hb);
    u32 mb = __float_as_uint(r) & 0xFFFF0000u;
    float r2 = r - __uint_as_float(mb);
    u32 lb = __float_as_uint(r2) & 0xFFFF0000u;
    h = (u16)(hb >> 16); m = (u16)(mb >> 16); l = (u16)(lb >> 16);
}

// ---------------------------------------------------------------------------
// Weight folding Wk = (lin_w @ post_w) -> 3-way bf16 split, frag-ordered with
// the K permutation + swizzle described above; bc = lin_b + lin_w@post_b;
// zero-inits cnt/logsum.
__global__ __launch_bounds__(256) void k_comb(const float* __restrict__ post_w,
                                              const float* __restrict__ lin_w,
                                              const float* __restrict__ post_b,
                                              const float* __restrict__ lin_b,
                                              u16* __restrict__ WkS,
                                              float* __restrict__ bcv,
                                              int* __restrict__ cnt,
                                              float* __restrict__ logsum) {
    int b = blockIdx.x, t = threadIdx.x;
    int zi = b * 256 + t;
    if (zi < N_NODES) cnt[zi] = 0;
    if (zi == 0) *logsum = 0.f;

    if (b < 624) {
        int c  = t & 63;
        int kl = t >> 6;
        int l  = b / 208;
        int o  = (b % 208) * 4 + kl;          // original K column in [0,832)
        const float* lw = lin_w + (size_t)l * 4096 + c * 64;
        const float* pw = post_w + (size_t)l * 53248 + o;
        float acc = 0.f;
        #pragma unroll 8
        for (int j = 0; j < 64; ++j)
            acc += lw[j] * pw[(size_t)j * 832];
        u16 h, m, lo;
        split1(acc, h, m, lo);

        // K permutation: o -> kn
        int kn;
        if (o < 64) kn = o;
        else {
            int s  = (o - 64) >> 8;           // 0 plain, 1 amp, 2 att
            int mm = (o - 64) & 255;          // aggr element index
            int j  = mm >> 5, r = mm & 31;
            kn = 64 + j * 96 + s * 32 + r;
        }
        int ch  = kn >> 5;
        int kin = kn & 31;
        int n16 = c & 15, nt = c >> 4;
        int swk = (((kin >> 3) + (n16 >> 1)) & 3) * 8 + (kin & 7);
        size_t base = (size_t)l * WKS_LAYER + (size_t)ch * 6144
                    + nt * 512 + n16 * 32 + swk;
        WkS[base]        = h;
        WkS[base + 2048] = m;
        WkS[base + 4096] = lo;
    } else if (t < 192) {
        int l = t >> 6, c = t & 63;
        float acc = lin_b[l * 64 + c];
        for (int j = 0; j < 64; ++j)
            acc += lin_w[(size_t)l * 4096 + c * 64 + j] * post_b[l * 64 + j];
        bcv[l * 64 + c] = acc;
    }
}

// ---------------------------------------------------------------------------
// CSR build: degree histogram
__global__ void k_count(const int* __restrict__ dst, int* __restrict__ cnt) {
    int e = blockIdx.x * 256 + threadIdx.x;
    if (e < N_EDGES) atomicAdd(&cnt[dst[e]], 1);
}

__global__ void k_chunk_sums(const int* __restrict__ cnt, int* __restrict__ bsum,
                             float* __restrict__ logsum) {
    __shared__ int   ired[256];
    __shared__ float lred[256];
    int b = blockIdx.x, t = threadIdx.x;
    int base = b * SCAN_CHUNK;
    int s = 0; float ls = 0.f;
    for (int i = t; i < SCAN_CHUNK; i += 256) {
        int idx = base + i;
        if (idx < N_NODES) {
            int v = cnt[idx];
            s += v;
            ls += logf((float)v + 1.0f);
        }
    }
    ired[t] = s; lred[t] = ls;
    __syncthreads();
    for (int off = 128; off > 0; off >>= 1) {
        if (t < off) { ired[t] += ired[t + off]; lred[t] += lred[t + off]; }
        __syncthreads();
    }
    if (t == 0) { bsum[b] = ired[0]; atomicAdd(logsum, lred[0]); }
}

__global__ void k_scan_top(const int* __restrict__ bsum, int* __restrict__ boff,
                           int* __restrict__ row_start) {
    if (threadIdx.x == 0) {
        int acc = 0;
        for (int i = 0; i < NCHUNKS; ++i) { boff[i] = acc; acc += bsum[i]; }
        row_start[N_NODES] = acc;
    }
}

__global__ void k_scan_chunks(const int* __restrict__ cnt, const int* __restrict__ boff,
                              int* __restrict__ row_start, int* __restrict__ cursor) {
    __shared__ int tsum[256];
    int b = blockIdx.x, t = threadIdx.x;
    int base = b * SCAN_CHUNK + t * 4;
    int v[4]; int s = 0;
    #pragma unroll
    for (int i = 0; i < 4; ++i) {
        int idx = base + i;
        v[i] = (idx < N_NODES) ? cnt[idx] : 0;
        s += v[i];
    }
    tsum[t] = s;
    __syncthreads();
    for (int off = 1; off < 256; off <<= 1) {
        int val = (t >= off) ? tsum[t - off] : 0;
        __syncthreads();
        tsum[t] += val;
        __syncthreads();
    }
    int excl = boff[b] + tsum[t] - s;
    #pragma unroll
    for (int i = 0; i < 4; ++i) {
        int idx = base + i;
        if (idx < N_NODES) { row_start[idx] = excl; cursor[idx] = excl; }
        excl += v[i];
    }
}

__global__ void k_scatter(const int* __restrict__ src, const int* __restrict__ dst,
                          int* __restrict__ cursor, int* __restrict__ csr_src) {
    int e = blockIdx.x * 256 + threadIdx.x;
    if (e < N_EDGES) {
        int d = dst[e];
        int slot = atomicAdd(&cursor[d], 1);
        csr_src[slot] = src[e];
    }
}

// per-node degree scalers; block 0 also zero-inits pooling accumulators
__global__ void k_scal(const int* __restrict__ cnt, const float* __restrict__ logsum,
                       float* __restrict__ inv_deg, float* __restrict__ ampv,
                       float* __restrict__ attv, float* __restrict__ g_sum,
                       int* __restrict__ g_cnt) {
    int n = blockIdx.x * 256 + threadIdx.x;
    if (blockIdx.x == 0) {
        for (int i = threadIdx.x; i < 4096; i += 256) g_sum[i] = 0.f;
        if (threadIdx.x < 64) g_cnt[threadIdx.x] = 0;
    }
    if (n < N_NODES) {
        float avg = logsum[0] / (float)N_NODES;
        float degf = fmaxf((float)cnt[n], 1.0f);
        inv_deg[n] = 1.0f / degf;
        float ld = logf(degf + 1.0f);
        ampv[n] = ld / avg;
        attv[n] = avg / ld;
    }
}

// ---------------------------------------------------------------------------
// p = x @ Wi^T + pre_b ; q = x @ Wj^T  (unchanged, passing r6 version)
__global__ __launch_bounds__(256) void k_pre(const float* __restrict__ x,
                                             const float* __restrict__ pre_w,
                                             const float* __restrict__ pre_b,
                                             float* __restrict__ p,
                                             float* __restrict__ q) {
    __shared__ float At[64][68];
    __shared__ float Wt[128][68];
    int t = threadIdx.x;
    int c4 = (t & 15) * 4;
    int r4 = (t >> 4) * 4;
    int rowBase = blockIdx.x * 64;
    int srow = t >> 2, skq = t & 3;

    #pragma unroll
    for (int pass = 0; pass < 4; ++pass) {
        int kk = (pass * 4 + skq) * 4;
        int row = rowBase + srow;
        float4 v = make_float4(0.f, 0.f, 0.f, 0.f);
        if (row < N_NODES) v = *(const float4*)&x[(size_t)row * 64 + kk];
        At[kk + 0][srow] = v.x;
        At[kk + 1][srow] = v.y;
        At[kk + 2][srow] = v.z;
        At[kk + 3][srow] = v.w;
    }
    for (int idx4 = t; idx4 < 2048; idx4 += 256) {
        int c = idx4 & 63, kq = idx4 >> 6;
        float4 v = *(const float4*)&pre_w[(size_t)c * 128 + kq * 4];
        Wt[kq * 4 + 0][c] = v.x;
        Wt[kq * 4 + 1][c] = v.y;
        Wt[kq * 4 + 2][c] = v.z;
        Wt[kq * 4 + 3][c] = v.w;
    }
    __syncthreads();

    float accp[4][4] = {{0}}, accq[4][4] = {{0}};
    #pragma unroll 4
    for (int kk = 0; kk < 64; ++kk) {
        float4 a  = *(const float4*)&At[kk][r4];
        float4 wp = *(const float4*)&Wt[kk][c4];
        float4 wq = *(const float4*)&Wt[64 + kk][c4];
        float av[4]  = {a.x, a.y, a.z, a.w};
        float wpv[4] = {wp.x, wp.y, wp.z, wp.w};
        float wqv[4] = {wq.x, wq.y, wq.z, wq.w};
        #pragma unroll
        for (int i = 0; i < 4; ++i)
            #pragma unroll
            for (int j = 0; j < 4; ++j) {
                accp[i][j] += av[i] * wpv[j];
                accq[i][j] += av[i] * wqv[j];
            }
    }
    float pb[4];
    #pragma unroll
    for (int j = 0; j < 4; ++j) pb[j] = pre_b[c4 + j];
    #pragma unroll
    for (int i = 0; i < 4; ++i) {
        int row = rowBase + r4 + i;
        if (row < N_NODES) {
            float4 vp = make_float4(accp[i][0] + pb[0], accp[i][1] + pb[1],
                                    accp[i][2] + pb[2], accp[i][3] + pb[3]);
            float4 vq = make_float4(accq[i][0], accq[i][1], accq[i][2], accq[i][3]);
            *(float4*)&p[row * 64 + c4] = vp;
            *(float4*)&q[row * 64 + c4] = vq;
        }
    }
}

// ---------------------------------------------------------------------------
// Aggregation (unchanged, passing r6 version)
__global__ __launch_bounds__(256) void k_aggr(const float* __restrict__ p,
                                              const float* __restrict__ q,
                                              const int* __restrict__ row_start,
                                              const int* __restrict__ csr_src,
                                              const float* __restrict__ inv_deg,
                                              float* __restrict__ aggr) {
    int wid  = (blockIdx.x * 256 + threadIdx.x) >> 6;
    int lane = threadIdx.x & 63;
    if (wid >= N_NODES) return;
    int n = wid;
    int beg = row_start[n], end = row_start[n + 1];
    float sum = 0.f, sq = 0.f;
    float mn = INFINITY, mx = -INFINITY;
    int e = beg;
    for (; e + 7 < end; e += 8) {
        float qv[8];
        #pragma unroll
        for (int u = 0; u < 8; ++u) {
            int s = csr_src[e + u];
            qv[u] = q[(size_t)s * 64 + lane];
        }
        #pragma unroll
        for (int u = 0; u < 8; ++u) {
            float m = qv[u];
            sum += m; sq += m * m;
            mn = fminf(mn, m); mx = fmaxf(mx, m);
        }
    }
    for (; e + 3 < end; e += 4) {
        float qv[4];
        #pragma unroll
        for (int u = 0; u < 4; ++u) {
            int s = csr_src[e + u];
            qv[u] = q[(size_t)s * 64 + lane];
        }
        #pragma unroll
        for (int u = 0; u < 4; ++u) {
            float m = qv[u];
            sum += m; sq += m * m;
            mn = fminf(mn, m); mx = fmaxf(mx, m);
        }
    }
    for (; e < end; ++e) {
        int s = csr_src[e];
        float m = q[(size_t)s * 64 + lane];
        sum += m; sq += m * m;
        mn = fminf(mn, m); mx = fmaxf(mx, m);
    }
    float* a = aggr + (size_t)n * 256;
    if (end <= beg) {
        a[lane]       = 0.f;
        a[64 + lane]  = 0.f;
        a[128 + lane] = 0.f;
        a[192 + lane] = sqrtf(EPS);
    } else {
        float pv = p[n * 64 + lane];
        float id = inv_deg[n];
        float meanq = sum * id;
        float var = fmaxf(sq * id - meanq * meanq, 0.f);
        a[lane]       = pv + meanq;
        a[64 + lane]  = pv + mn;
        a[128 + lane] = pv + mx;
        a[192 + lane] = sqrtf(var + EPS);
    }
}

// ---------------------------------------------------------------------------
// MFMA k_post v2: B double-buffered through LDS (staged once per block),
// A loaded once per 32-col group and re-scaled/re-split for plain/amp/att.
// 6-MFMA exact 3-way bf16 split (error ~2^-24). Wave w = rows [16w,16w+16).
__global__ __launch_bounds__(256) void k_post(const float* __restrict__ x,
                                              const float* __restrict__ aggr,
                                              const float* __restrict__ ampv,
                                              const float* __restrict__ attv,
                                              const u16* __restrict__ WkS,
                                              const float* __restrict__ bc,
                                              float* __restrict__ xout) {
    __shared__ u16 ldsB[2 * 6144];
    int t = threadIdx.x;
    int w = t >> 6;
    int lane = t & 63;
    int m = lane & 15;
    int qh = lane >> 4;
    int rowBase = blockIdx.x * 64;

    int myrow = rowBase + 16 * w + m;
    bool vr = myrow < N_NODES;
    float ampR = vr ? ampv[myrow] : 0.f;
    float attR = vr ? attv[myrow] : 0.f;
    const float* xrow = x + (size_t)(vr ? myrow : 0) * 64;
    const float* arow = aggr + (size_t)(vr ? myrow : 0) * 256;

    // swizzled B-fragment lane offset within a [16 n][32 k] u16 tile
    int bo = m * 32 + ((qh + (m >> 1)) & 3) * 8;

    floatx4 acc[4] = {};
    float4 stg[3];
    float fc[8], fn[8];
    #pragma unroll
    for (int i = 0; i < 8; ++i) { fc[i] = 0.f; fn[i] = 0.f; }

    auto stageLoad = [&](int ch) {
        const float4* gsrc = (const float4*)(WkS + (size_t)ch * 6144);
        #pragma unroll
        for (int i = 0; i < 3; ++i) stg[i] = gsrc[i * 256 + t];
    };
    auto stageWrite = [&](int buf) {
        float4* d = (float4*)(ldsB + buf * 6144);
        #pragma unroll
        for (int i = 0; i < 3; ++i) d[i * 256 + t] = stg[i];
    };
    auto loadRaw = [&](const float* sp, float* f) {   // 32B contiguous
        if (!vr) {
            #pragma unroll
            for (int i = 0; i < 8; ++i) f[i] = 0.f;
            return;
        }
        float4 u0 = *(const float4*)sp;
        float4 u1 = *(const float4*)(sp + 4);
        f[0] = u0.x; f[1] = u0.y; f[2] = u0.z; f[3] = u0.w;
        f[4] = u1.x; f[5] = u1.y; f[6] = u1.z; f[7] = u1.w;
    };

    // prologue: stage chunk 0, load x chunk 0
    stageLoad(0);
    stageWrite(0);
    loadRaw(xrow + qh * 8, fc);
    __syncthreads();

    for (int ch = 0; ch < 26; ++ch) {
        // issue global loads for next B chunk (written to LDS after compute)
        if (ch + 1 < 26) stageLoad(ch + 1);

        // A prefetch for next source group
        if (ch == 0)      loadRaw(xrow + 32 + qh * 8, fn);
        else if (ch == 1) loadRaw(arow + qh * 8, fn);
        else {
            int j = (ch - 2) / 3, s = (ch - 2) % 3;
            if (s == 2 && j < 7) loadRaw(arow + (j + 1) * 32 + qh * 8, fn);
        }

        float sc = 1.f;
        if (ch >= 2) {
            int s = (ch - 2) % 3;
            sc = (s == 0) ? 1.f : ((s == 1) ? ampR : attR);
        }

        // scale + exact 3-way split
        union { u32 u[4]; short8 s8; } AH, AM, AL;
        #pragma unroll
        for (int i = 0; i < 4; ++i) {
            float f0 = fc[2 * i] * sc, f1 = fc[2 * i + 1] * sc;
            u32 b0 = __float_as_uint(f0), b1 = __float_as_uint(f1);
            u32 h0 = b0 & 0xFFFF0000u,  h1 = b1 & 0xFFFF0000u;
            float r0 = f0 - __uint_as_float(h0);
            float r1 = f1 - __uint_as_float(h1);
            u32 m0 = __float_as_uint(r0) & 0xFFFF0000u;
            u32 m1 = __float_as_uint(r1) & 0xFFFF0000u;
            float s0 = r0 - __uint_as_float(m0);
            float s1 = r1 - __uint_as_float(m1);
            u32 l0 = __float_as_uint(s0) & 0xFFFF0000u;
            u32 l1 = __float_as_uint(s1) & 0xFFFF0000u;
            AH.u[i] = (h0 >> 16) | h1;
            AM.u[i] = (m0 >> 16) | m1;
            AL.u[i] = (l0 >> 16) | l1;
        }

        const u16* Bb = ldsB + (ch & 1) * 6144;
        #pragma unroll
        for (int nt = 0; nt < 4; ++nt) {
            short8 bH = *(const short8*)(Bb + nt * 512 + bo);
            short8 bM = *(const short8*)(Bb + 2048 + nt * 512 + bo);
            short8 bL = *(const short8*)(Bb + 4096 + nt * 512 + bo);
            acc[nt] = __builtin_amdgcn_mfma_f32_16x16x32_bf16(AH.s8, bH, acc[nt], 0, 0, 0);
            acc[nt] = __builtin_amdgcn_mfma_f32_16x16x32_bf16(AH.s8, bM, acc[nt], 0, 0, 0);
            acc[nt] = __builtin_amdgcn_mfma_f32_16x16x32_bf16(AM.s8, bH, acc[nt], 0, 0, 0);
            acc[nt] = __builtin_amdgcn_mfma_f32_16x16x32_bf16(AH.s8, bL, acc[nt], 0, 0, 0);
            acc[nt] = __builtin_amdgcn_mfma_f32_16x16x32_bf16(AM.s8, bM, acc[nt], 0, 0, 0);
            acc[nt] = __builtin_amdgcn_mfma_f32_16x16x32_bf16(AL.s8, bH, acc[nt], 0, 0, 0);
        }

        if (ch + 1 < 26) stageWrite((ch + 1) & 1);
        __syncthreads();

        // advance A registers when the source group changes
        bool adv = (ch < 2) || ((ch - 2) % 3 == 2);
        if (adv) {
            #pragma unroll
            for (int i = 0; i < 8; ++i) fc[i] = fn[i];
        }
    }

    // epilogue: C/D layout col = lane&15, row = (lane>>4)*4 + reg
    int col = lane & 15;
    #pragma unroll
    for (int nt = 0; nt < 4; ++nt) {
        float bias = bc[nt * 16 + col];
        #pragma unroll
        for (int reg = 0; reg < 4; ++reg) {
            int grow = rowBase + 16 * w + qh * 4 + reg;
            if (grow < N_NODES) {
                xout[(size_t)grow * 64 + nt * 16 + col] =
                    fmaxf(acc[nt][reg] + bias, 0.f);
            }
        }
    }
}

// ---------------------------------------------------------------------------
__global__ __launch_bounds__(256) void k_pool(const float* __restrict__ x,
                                              const int* __restrict__ batch,
                                              float* __restrict__ g_sum,
                                              int* __restrict__ g_cnt) {
    int lane = threadIdx.x & 63;
    int wave = blockIdx.x * 4 + (threadIdx.x >> 6);
    const int NPW = 128;
    int beg = wave * NPW;
    if (beg >= N_NODES) return;
    int end = min(beg + NPW, N_NODES);
    float acc = 0.f;
    int cur = batch[beg];
    int c = 0;
    for (int n = beg; n < end; ++n) {
        int b = batch[n];
        if (b != cur) {
            atomicAdd(&g_sum[cur * 64 + lane], acc);
            if (lane == 0) atomicAdd(&g_cnt[cur], c);
            acc = 0.f; c = 0; cur = b;
        }
        acc += x[n * 64 + lane];
        ++c;
    }
    atomicAdd(&g_sum[cur * 64 + lane], acc);
    if (lane == 0) atomicAdd(&g_cnt[cur], c);
}

__global__ __launch_bounds__(256) void k_mlp(const float* __restrict__ g_sum,
                                             const int* __restrict__ g_cnt,
                                             const float* __restrict__ w1,
                                             const float* __restrict__ b1,
                                             const float* __restrict__ w2,
                                             const float* __restrict__ b2,
                                             float* __restrict__ out) {
    __shared__ float g[64][64];
    __shared__ float h[64][64];
    __shared__ float wT[64][65];
    int t = threadIdx.x;
    for (int idx = t; idx < 4096; idx += 256) {
        int gi = idx >> 6, c = idx & 63;
        float cntf = fmaxf((float)g_cnt[gi], 1.f);
        g[gi][c] = g_sum[idx] / cntf;
    }
    for (int idx = t; idx < 4096; idx += 256) {
        int c = idx >> 6, k = idx & 63;
        wT[k][c] = w1[c * 64 + k];
    }
    __syncthreads();
    for (int idx = t; idx < 4096; idx += 256) {
        int gi = idx >> 6, c = idx & 63;
        float acc = b1[c];
        for (int k = 0; k < 64; ++k) acc += g[gi][k] * wT[k][c];
        h[gi][c] = fmaxf(acc, 0.f);
    }
    __syncthreads();
    for (int idx = t; idx < 64 * NCLASSES; idx += 256) {
        int gi = idx >> 4, c = idx & 15;
        float acc = b2[c];
        for (int k = 0; k < 64; ++k) acc += h[gi][k] * w2[c * 64 + k];
        out[gi * NCLASSES + c] = acc;
    }
}

// ---------------------------------------------------------------------------
extern "C" void kernel_launch(void* const* d_in, const int* in_sizes, int n_in,
                              void* d_out, int out_size, void* d_ws, size_t ws_size,
                              hipStream_t stream) {
    const float* x      = (const float*)d_in[0];
    const int*   ei     = (const int*)d_in[1];
    const int*   batch  = (const int*)d_in[2];
    const float* pre_w  = (const float*)d_in[3];
    const float* pre_b  = (const float*)d_in[4];
    const float* post_w = (const float*)d_in[5];
    const float* post_b = (const float*)d_in[6];
    const float* lin_w  = (const float*)d_in[7];
    const float* lin_b  = (const float*)d_in[8];
    const float* mlp_w1 = (const float*)d_in[9];
    const float* mlp_b1 = (const float*)d_in[10];
    const float* mlp_w2 = (const float*)d_in[11];
    const float* mlp_b2 = (const float*)d_in[12];

    const int* src = ei;
    const int* dst = ei + N_EDGES;

    char* base = (char*)d_ws;
    size_t off = 0;
    auto alloc = [&](size_t bytes) -> void* {
        void* ptr = base + off;
        off += (bytes + 255) & ~(size_t)255;
        return ptr;
    };
    int*   cnt       = (int*)alloc(N_NODES * 4);
    int*   row_start = (int*)alloc((N_NODES + 1) * 4);
    int*   cursor    = (int*)alloc(N_NODES * 4);
    int*   csr_src   = (int*)alloc(N_EDGES * 4);
    int*   bsum      = (int*)alloc(64 * 4);
    int*   boff      = (int*)alloc(64 * 4);
    float* logsum    = (float*)alloc(16);
    float* inv_deg   = (float*)alloc(N_NODES * 4);
    float* ampv      = (float*)alloc(N_NODES * 4);
    float* attv      = (float*)alloc(N_NODES * 4);
    float* p         = (float*)alloc((size_t)N_NODES * 64 * 4);
    float* q         = (float*)alloc((size_t)N_NODES * 64 * 4);
    float* aggr      = (float*)alloc((size_t)N_NODES * 256 * 4);
    float* xb0       = (float*)alloc((size_t)N_NODES * 64 * 4);
    float* xb1       = (float*)alloc((size_t)N_NODES * 64 * 4);
    float* g_sum     = (float*)alloc(64 * 64 * 4);
    int*   g_cnt     = (int*)alloc(64 * 4);
    u16*   WkS       = (u16*)alloc((size_t)3 * WKS_LAYER * 2);
    float* bcv       = (float*)alloc(3 * 64 * 4);

    // weight folding (pre-split bf16, frag-ordered, K-permuted) + zero-init
    k_comb<<<625, 256, 0, stream>>>(post_w, lin_w, post_b, lin_b, WkS, bcv,
                                    cnt, logsum);

    k_count<<<(N_EDGES + 255) / 256, 256, 0, stream>>>(dst, cnt);
    k_chunk_sums<<<NCHUNKS, 256, 0, stream>>>(cnt, bsum, logsum);
    k_scan_top<<<1, 64, 0, stream>>>(bsum, boff, row_start);
    k_scan_chunks<<<NCHUNKS, 256, 0, stream>>>(cnt, boff, row_start, cursor);
    k_scatter<<<(N_EDGES + 255) / 256, 256, 0, stream>>>(src, dst, cursor, csr_src);
    k_scal<<<(N_NODES + 255) / 256, 256, 0, stream>>>(cnt, logsum, inv_deg,
                                                      ampv, attv, g_sum, g_cnt);

    const int GEMM_BLOCKS = (N_NODES + 63) / 64;   // 782
    const float* xin = x;
    float* bufs[3] = {xb0, xb1, xb0};
    for (int l = 0; l < NLAYERS; ++l) {
        k_pre<<<GEMM_BLOCKS, 256, 0, stream>>>(xin, pre_w + (size_t)l * 64 * 128,
                                               pre_b + l * 64, p, q);
        k_aggr<<<(N_NODES + 3) / 4, 256, 0, stream>>>(p, q, row_start, csr_src,
                                                      inv_deg, aggr);
        float* xo = bufs[l];
        k_post<<<GEMM_BLOCKS, 256, 0, stream>>>(xin, aggr, ampv, attv,
                                                WkS + (size_t)l * WKS_LAYER,
                                                bcv + l * 64, xo);
        xin = xo;
    }

    int pool_waves = (N_NODES + 127) / 128;
    k_pool<<<(pool_waves + 3) / 4, 256, 0, stream>>>(xin, batch, g_sum, g_cnt);
    k_mlp<<<1, 256, 0, stream>>>(g_sum, g_cnt, mlp_w1, mlp_b1, mlp_w2, mlp_b2,
                                 (float*)d_out);
}

// Round 9
// 556.056 us; speedup vs baseline: 1.2911x; 1.2634x over previous
//
#include <hip/hip_runtime.h>
#include <math.h>

#define N_NODES   50000
#define N_EDGES   800000
#define NUM_GRAPHS 64
#define FDIM      64
#define HDIM      64
#define NLAYERS   3
#define NCLASSES  16
#define EPS       1e-5f

#define SCAN_CHUNK 1024
#define NCHUNKS ((N_NODES + SCAN_CHUNK - 1) / SCAN_CHUNK)   // 49

typedef unsigned short u16;
typedef unsigned int   u32;
typedef __attribute__((ext_vector_type(8))) short short8;   // 8 bf16 (4 VGPRs)
typedef __attribute__((ext_vector_type(4))) float floatx4;  // MFMA accum

// WkS layout per layer (u16 bf16 bits):
//   [26 kchunk][3 split][4 ntile][16 n][32 k-swizzled] -> 159744 u16 per layer
// K-order: chunks 0-1 = x cols 0..63; then for aggr group j (j=0..7, 32 cols):
//   chunk 2+3j+0 = plain, +1 = amp, +2 = att.
// k position within a chunk row is swizzled: element (n16, kin=qh*8+jj) stored
// at n16*32 + ((qh + (n16>>1)) & 3)*8 + jj   (2-way LDS bank spread on read).
#define WKS_LAYER 159744

// ---------------------------------------------------------------------------
__device__ inline void split1(float f, u16& h, u16& m, u16& l) {
    u32 b  = __float_as_uint(f);
    u32 hb = b & 0xFFFF0000u;
    float r = f - __uint_as_float(hb);
    u32 mb = __float_as_uint(r) & 0xFFFF0000u;
    float r2 = r - __uint_as_float(mb);
    u32 lb = __float_as_uint(r2) & 0xFFFF0000u;
    h = (u16)(hb >> 16); m = (u16)(mb >> 16); l = (u16)(lb >> 16);
}

// async global->LDS DMA, 16B per lane (dest = wave-uniform base + lane*16)
__device__ inline void gl_lds16(const void* g, void* l) {
    __builtin_amdgcn_global_load_lds(
        (const __attribute__((address_space(1))) u32*)g,
        (__attribute__((address_space(3))) u32*)l, 16, 0, 0);
}

// ---------------------------------------------------------------------------
// Weight folding Wk = (lin_w @ post_w) -> 3-way bf16 split, frag-ordered with
// the K permutation + swizzle described above; bc = lin_b + lin_w@post_b;
// zero-inits cnt/logsum.
__global__ __launch_bounds__(256) void k_comb(const float* __restrict__ post_w,
                                              const float* __restrict__ lin_w,
                                              const float* __restrict__ post_b,
                                              const float* __restrict__ lin_b,
                                              u16* __restrict__ WkS,
                                              float* __restrict__ bcv,
                                              int* __restrict__ cnt,
                                              float* __restrict__ logsum) {
    int b = blockIdx.x, t = threadIdx.x;
    int zi = b * 256 + t;
    if (zi < N_NODES) cnt[zi] = 0;
    if (zi == 0) *logsum = 0.f;

    if (b < 624) {
        int c  = t & 63;
        int kl = t >> 6;
        int l  = b / 208;
        int o  = (b % 208) * 4 + kl;          // original K column in [0,832)
        const float* lw = lin_w + (size_t)l * 4096 + c * 64;
        const float* pw = post_w + (size_t)l * 53248 + o;
        float acc = 0.f;
        #pragma unroll 8
        for (int j = 0; j < 64; ++j)
            acc += lw[j] * pw[(size_t)j * 832];
        u16 h, m, lo;
        split1(acc, h, m, lo);

        // K permutation: o -> kn
        int kn;
        if (o < 64) kn = o;
        else {
            int s  = (o - 64) >> 8;           // 0 plain, 1 amp, 2 att
            int mm = (o - 64) & 255;          // aggr element index
            int j  = mm >> 5, r = mm & 31;
            kn = 64 + j * 96 + s * 32 + r;
        }
        int ch  = kn >> 5;
        int kin = kn & 31;
        int n16 = c & 15, nt = c >> 4;
        int swk = (((kin >> 3) + (n16 >> 1)) & 3) * 8 + (kin & 7);
        size_t base = (size_t)l * WKS_LAYER + (size_t)ch * 6144
                    + nt * 512 + n16 * 32 + swk;
        WkS[base]        = h;
        WkS[base + 2048] = m;
        WkS[base + 4096] = lo;
    } else if (t < 192) {
        int l = t >> 6, c = t & 63;
        float acc = lin_b[l * 64 + c];
        for (int j = 0; j < 64; ++j)
            acc += lin_w[(size_t)l * 4096 + c * 64 + j] * post_b[l * 64 + j];
        bcv[l * 64 + c] = acc;
    }
}

// ---------------------------------------------------------------------------
// CSR build: degree histogram
__global__ void k_count(const int* __restrict__ dst, int* __restrict__ cnt) {
    int e = blockIdx.x * 256 + threadIdx.x;
    if (e < N_EDGES) atomicAdd(&cnt[dst[e]], 1);
}

__global__ void k_chunk_sums(const int* __restrict__ cnt, int* __restrict__ bsum,
                             float* __restrict__ logsum) {
    __shared__ int   ired[256];
    __shared__ float lred[256];
    int b = blockIdx.x, t = threadIdx.x;
    int base = b * SCAN_CHUNK;
    int s = 0; float ls = 0.f;
    for (int i = t; i < SCAN_CHUNK; i += 256) {
        int idx = base + i;
        if (idx < N_NODES) {
            int v = cnt[idx];
            s += v;
            ls += logf((float)v + 1.0f);
        }
    }
    ired[t] = s; lred[t] = ls;
    __syncthreads();
    for (int off = 128; off > 0; off >>= 1) {
        if (t < off) { ired[t] += ired[t + off]; lred[t] += lred[t + off]; }
        __syncthreads();
    }
    if (t == 0) { bsum[b] = ired[0]; atomicAdd(logsum, lred[0]); }
}

__global__ void k_scan_top(const int* __restrict__ bsum, int* __restrict__ boff,
                           int* __restrict__ row_start) {
    if (threadIdx.x == 0) {
        int acc = 0;
        for (int i = 0; i < NCHUNKS; ++i) { boff[i] = acc; acc += bsum[i]; }
        row_start[N_NODES] = acc;
    }
}

__global__ void k_scan_chunks(const int* __restrict__ cnt, const int* __restrict__ boff,
                              int* __restrict__ row_start, int* __restrict__ cursor) {
    __shared__ int tsum[256];
    int b = blockIdx.x, t = threadIdx.x;
    int base = b * SCAN_CHUNK + t * 4;
    int v[4]; int s = 0;
    #pragma unroll
    for (int i = 0; i < 4; ++i) {
        int idx = base + i;
        v[i] = (idx < N_NODES) ? cnt[idx] : 0;
        s += v[i];
    }
    tsum[t] = s;
    __syncthreads();
    for (int off = 1; off < 256; off <<= 1) {
        int val = (t >= off) ? tsum[t - off] : 0;
        __syncthreads();
        tsum[t] += val;
        __syncthreads();
    }
    int excl = boff[b] + tsum[t] - s;
    #pragma unroll
    for (int i = 0; i < 4; ++i) {
        int idx = base + i;
        if (idx < N_NODES) { row_start[idx] = excl; cursor[idx] = excl; }
        excl += v[i];
    }
}

__global__ void k_scatter(const int* __restrict__ src, const int* __restrict__ dst,
                          int* __restrict__ cursor, int* __restrict__ csr_src) {
    int e = blockIdx.x * 256 + threadIdx.x;
    if (e < N_EDGES) {
        int d = dst[e];
        int slot = atomicAdd(&cursor[d], 1);
        csr_src[slot] = src[e];
    }
}

// per-node degree scalers; block 0 also zero-inits pooling accumulators
__global__ void k_scal(const int* __restrict__ cnt, const float* __restrict__ logsum,
                       float* __restrict__ inv_deg, float* __restrict__ ampv,
                       float* __restrict__ attv, float* __restrict__ g_sum,
                       int* __restrict__ g_cnt) {
    int n = blockIdx.x * 256 + threadIdx.x;
    if (blockIdx.x == 0) {
        for (int i = threadIdx.x; i < 4096; i += 256) g_sum[i] = 0.f;
        if (threadIdx.x < 64) g_cnt[threadIdx.x] = 0;
    }
    if (n < N_NODES) {
        float avg = logsum[0] / (float)N_NODES;
        float degf = fmaxf((float)cnt[n], 1.0f);
        inv_deg[n] = 1.0f / degf;
        float ld = logf(degf + 1.0f);
        ampv[n] = ld / avg;
        attv[n] = avg / ld;
    }
}

// ---------------------------------------------------------------------------
// p = x @ Wi^T + pre_b ; q = x @ Wj^T  (unchanged, passing r6 version)
__global__ __launch_bounds__(256) void k_pre(const float* __restrict__ x,
                                             const float* __restrict__ pre_w,
                                             const float* __restrict__ pre_b,
                                             float* __restrict__ p,
                                             float* __restrict__ q) {
    __shared__ float At[64][68];
    __shared__ float Wt[128][68];
    int t = threadIdx.x;
    int c4 = (t & 15) * 4;
    int r4 = (t >> 4) * 4;
    int rowBase = blockIdx.x * 64;
    int srow = t >> 2, skq = t & 3;

    #pragma unroll
    for (int pass = 0; pass < 4; ++pass) {
        int kk = (pass * 4 + skq) * 4;
        int row = rowBase + srow;
        float4 v = make_float4(0.f, 0.f, 0.f, 0.f);
        if (row < N_NODES) v = *(const float4*)&x[(size_t)row * 64 + kk];
        At[kk + 0][srow] = v.x;
        At[kk + 1][srow] = v.y;
        At[kk + 2][srow] = v.z;
        At[kk + 3][srow] = v.w;
    }
    for (int idx4 = t; idx4 < 2048; idx4 += 256) {
        int c = idx4 & 63, kq = idx4 >> 6;
        float4 v = *(const float4*)&pre_w[(size_t)c * 128 + kq * 4];
        Wt[kq * 4 + 0][c] = v.x;
        Wt[kq * 4 + 1][c] = v.y;
        Wt[kq * 4 + 2][c] = v.z;
        Wt[kq * 4 + 3][c] = v.w;
    }
    __syncthreads();

    float accp[4][4] = {{0}}, accq[4][4] = {{0}};
    #pragma unroll 4
    for (int kk = 0; kk < 64; ++kk) {
        float4 a  = *(const float4*)&At[kk][r4];
        float4 wp = *(const float4*)&Wt[kk][c4];
        float4 wq = *(const float4*)&Wt[64 + kk][c4];
        float av[4]  = {a.x, a.y, a.z, a.w};
        float wpv[4] = {wp.x, wp.y, wp.z, wp.w};
        float wqv[4] = {wq.x, wq.y, wq.z, wq.w};
        #pragma unroll
        for (int i = 0; i < 4; ++i)
            #pragma unroll
            for (int j = 0; j < 4; ++j) {
                accp[i][j] += av[i] * wpv[j];
                accq[i][j] += av[i] * wqv[j];
            }
    }
    float pb[4];
    #pragma unroll
    for (int j = 0; j < 4; ++j) pb[j] = pre_b[c4 + j];
    #pragma unroll
    for (int i = 0; i < 4; ++i) {
        int row = rowBase + r4 + i;
        if (row < N_NODES) {
            float4 vp = make_float4(accp[i][0] + pb[0], accp[i][1] + pb[1],
                                    accp[i][2] + pb[2], accp[i][3] + pb[3]);
            float4 vq = make_float4(accq[i][0], accq[i][1], accq[i][2], accq[i][3]);
            *(float4*)&p[row * 64 + c4] = vp;
            *(float4*)&q[row * 64 + c4] = vq;
        }
    }
}

// ---------------------------------------------------------------------------
// Aggregation (unchanged, passing r6 version)
__global__ __launch_bounds__(256) void k_aggr(const float* __restrict__ p,
                                              const float* __restrict__ q,
                                              const int* __restrict__ row_start,
                                              const int* __restrict__ csr_src,
                                              const float* __restrict__ inv_deg,
                                              float* __restrict__ aggr) {
    int wid  = (blockIdx.x * 256 + threadIdx.x) >> 6;
    int lane = threadIdx.x & 63;
    if (wid >= N_NODES) return;
    int n = wid;
    int beg = row_start[n], end = row_start[n + 1];
    float sum = 0.f, sq = 0.f;
    float mn = INFINITY, mx = -INFINITY;
    int e = beg;
    for (; e + 7 < end; e += 8) {
        float qv[8];
        #pragma unroll
        for (int u = 0; u < 8; ++u) {
            int s = csr_src[e + u];
            qv[u] = q[(size_t)s * 64 + lane];
        }
        #pragma unroll
        for (int u = 0; u < 8; ++u) {
            float m = qv[u];
            sum += m; sq += m * m;
            mn = fminf(mn, m); mx = fmaxf(mx, m);
        }
    }
    for (; e + 3 < end; e += 4) {
        float qv[4];
        #pragma unroll
        for (int u = 0; u < 4; ++u) {
            int s = csr_src[e + u];
            qv[u] = q[(size_t)s * 64 + lane];
        }
        #pragma unroll
        for (int u = 0; u < 4; ++u) {
            float m = qv[u];
            sum += m; sq += m * m;
            mn = fminf(mn, m); mx = fmaxf(mx, m);
        }
    }
    for (; e < end; ++e) {
        int s = csr_src[e];
        float m = q[(size_t)s * 64 + lane];
        sum += m; sq += m * m;
        mn = fminf(mn, m); mx = fmaxf(mx, m);
    }
    float* a = aggr + (size_t)n * 256;
    if (end <= beg) {
        a[lane]       = 0.f;
        a[64 + lane]  = 0.f;
        a[128 + lane] = 0.f;
        a[192 + lane] = sqrtf(EPS);
    } else {
        float pv = p[n * 64 + lane];
        float id = inv_deg[n];
        float meanq = sum * id;
        float var = fmaxf(sq * id - meanq * meanq, 0.f);
        a[lane]       = pv + meanq;
        a[64 + lane]  = pv + mn;
        a[128 + lane] = pv + mx;
        a[192 + lane] = sqrtf(var + EPS);
    }
}

// ---------------------------------------------------------------------------
// MFMA k_post v3: B staged via async global_load_lds DMA (no VGPR staging,
// no spill), double-buffered; A loaded once per 32-col group and
// re-scaled/re-split for plain/amp/att. 6-MFMA exact 3-way bf16 split.
__global__ __launch_bounds__(256, 4) void k_post(const float* __restrict__ x,
                                                 const float* __restrict__ aggr,
                                                 const float* __restrict__ ampv,
                                                 const float* __restrict__ attv,
                                                 const u16* __restrict__ WkS,
                                                 const float* __restrict__ bc,
                                                 float* __restrict__ xout) {
    __shared__ u16 ldsB[2 * 6144];
    int t = threadIdx.x;
    int w = t >> 6;
    int lane = t & 63;
    int m = lane & 15;
    int qh = lane >> 4;
    int rowBase = blockIdx.x * 64;

    int myrow = rowBase + 16 * w + m;
    bool vr = myrow < N_NODES;
    float ampR = vr ? ampv[myrow] : 0.f;
    float attR = vr ? attv[myrow] : 0.f;
    const float* xrow = x + (size_t)(vr ? myrow : 0) * 64;
    const float* arow = aggr + (size_t)(vr ? myrow : 0) * 256;

    // swizzled B-fragment lane offset within a [16 n][32 k] u16 tile
    int bo = m * 32 + ((qh + (m >> 1)) & 3) * 8;

    floatx4 acc[4] = {};
    float fc[8], fn[8];
    #pragma unroll
    for (int i = 0; i < 8; ++i) { fc[i] = 0.f; fn[i] = 0.f; }

    // async DMA of one 12288B B-chunk: wave w copies bytes [3072w, 3072w+3072)
    auto stageIssue = [&](int ch, int buf) {
        const char* g = (const char*)WkS + (size_t)ch * 12288 + w * 3072 + lane * 16;
        char* l = (char*)ldsB + buf * 12288 + w * 3072;   // wave-uniform base
        #pragma unroll
        for (int i = 0; i < 3; ++i)
            gl_lds16(g + i * 1024, l + i * 1024);
    };
    auto loadRaw = [&](const float* sp, float* f) {   // 32B contiguous
        if (!vr) {
            #pragma unroll
            for (int i = 0; i < 8; ++i) f[i] = 0.f;
            return;
        }
        float4 u0 = *(const float4*)sp;
        float4 u1 = *(const float4*)(sp + 4);
        f[0] = u0.x; f[1] = u0.y; f[2] = u0.z; f[3] = u0.w;
        f[4] = u1.x; f[5] = u1.y; f[6] = u1.z; f[7] = u1.w;
    };

    // prologue: DMA chunk 0, load x chunk 0
    stageIssue(0, 0);
    loadRaw(xrow + qh * 8, fc);
    asm volatile("s_waitcnt vmcnt(0)" ::: "memory");
    __syncthreads();

    for (int ch = 0; ch < 26; ++ch) {
        // async DMA for next B chunk — in flight during this chunk's compute
        if (ch + 1 < 26) stageIssue(ch + 1, (ch + 1) & 1);

        // A prefetch for next source group
        if (ch == 0)      loadRaw(xrow + 32 + qh * 8, fn);
        else if (ch == 1) loadRaw(arow + qh * 8, fn);
        else {
            int j = (ch - 2) / 3, s = (ch - 2) % 3;
            if (s == 2 && j < 7) loadRaw(arow + (j + 1) * 32 + qh * 8, fn);
        }

        float sc = 1.f;
        if (ch >= 2) {
            int s = (ch - 2) % 3;
            sc = (s == 0) ? 1.f : ((s == 1) ? ampR : attR);
        }

        // scale + exact 3-way split
        union { u32 u[4]; short8 s8; } AH, AM, AL;
        #pragma unroll
        for (int i = 0; i < 4; ++i) {
            float f0 = fc[2 * i] * sc, f1 = fc[2 * i + 1] * sc;
            u32 b0 = __float_as_uint(f0), b1 = __float_as_uint(f1);
            u32 h0 = b0 & 0xFFFF0000u,  h1 = b1 & 0xFFFF0000u;
            float r0 = f0 - __uint_as_float(h0);
            float r1 = f1 - __uint_as_float(h1);
            u32 m0 = __float_as_uint(r0) & 0xFFFF0000u;
            u32 m1 = __float_as_uint(r1) & 0xFFFF0000u;
            float s0 = r0 - __uint_as_float(m0);
            float s1 = r1 - __uint_as_float(m1);
            u32 l0 = __float_as_uint(s0) & 0xFFFF0000u;
            u32 l1 = __float_as_uint(s1) & 0xFFFF0000u;
            AH.u[i] = (h0 >> 16) | h1;
            AM.u[i] = (m0 >> 16) | m1;
            AL.u[i] = (l0 >> 16) | l1;
        }

        const u16* Bb = ldsB + (ch & 1) * 6144;
        #pragma unroll
        for (int nt = 0; nt < 4; ++nt) {
            short8 bH = *(const short8*)(Bb + nt * 512 + bo);
            short8 bM = *(const short8*)(Bb + 2048 + nt * 512 + bo);
            short8 bL = *(const short8*)(Bb + 4096 + nt * 512 + bo);
            acc[nt] = __builtin_amdgcn_mfma_f32_16x16x32_bf16(AH.s8, bH, acc[nt], 0, 0, 0);
            acc[nt] = __builtin_amdgcn_mfma_f32_16x16x32_bf16(AH.s8, bM, acc[nt], 0, 0, 0);
            acc[nt] = __builtin_amdgcn_mfma_f32_16x16x32_bf16(AM.s8, bH, acc[nt], 0, 0, 0);
            acc[nt] = __builtin_amdgcn_mfma_f32_16x16x32_bf16(AH.s8, bL, acc[nt], 0, 0, 0);
            acc[nt] = __builtin_amdgcn_mfma_f32_16x16x32_bf16(AM.s8, bM, acc[nt], 0, 0, 0);
            acc[nt] = __builtin_amdgcn_mfma_f32_16x16x32_bf16(AL.s8, bH, acc[nt], 0, 0, 0);
        }

        // drain the DMA into buf^1, then make it visible to all waves
        asm volatile("s_waitcnt vmcnt(0)" ::: "memory");
        __syncthreads();

        // advance A registers when the source group changes
        bool adv = (ch < 2) || ((ch - 2) % 3 == 2);
        if (adv) {
            #pragma unroll
            for (int i = 0; i < 8; ++i) fc[i] = fn[i];
        }
    }

    // epilogue: C/D layout col = lane&15, row = (lane>>4)*4 + reg
    int col = lane & 15;
    #pragma unroll
    for (int nt = 0; nt < 4; ++nt) {
        float bias = bc[nt * 16 + col];
        #pragma unroll
        for (int reg = 0; reg < 4; ++reg) {
            int grow = rowBase + 16 * w + qh * 4 + reg;
            if (grow < N_NODES) {
                xout[(size_t)grow * 64 + nt * 16 + col] =
                    fmaxf(acc[nt][reg] + bias, 0.f);
            }
        }
    }
}

// ---------------------------------------------------------------------------
__global__ __launch_bounds__(256) void k_pool(const float* __restrict__ x,
                                              const int* __restrict__ batch,
                                              float* __restrict__ g_sum,
                                              int* __restrict__ g_cnt) {
    int lane = threadIdx.x & 63;
    int wave = blockIdx.x * 4 + (threadIdx.x >> 6);
    const int NPW = 128;
    int beg = wave * NPW;
    if (beg >= N_NODES) return;
    int end = min(beg + NPW, N_NODES);
    float acc = 0.f;
    int cur = batch[beg];
    int c = 0;
    for (int n = beg; n < end; ++n) {
        int b = batch[n];
        if (b != cur) {
            atomicAdd(&g_sum[cur * 64 + lane], acc);
            if (lane == 0) atomicAdd(&g_cnt[cur], c);
            acc = 0.f; c = 0; cur = b;
        }
        acc += x[n * 64 + lane];
        ++c;
    }
    atomicAdd(&g_sum[cur * 64 + lane], acc);
    if (lane == 0) atomicAdd(&g_cnt[cur], c);
}

__global__ __launch_bounds__(256) void k_mlp(const float* __restrict__ g_sum,
                                             const int* __restrict__ g_cnt,
                                             const float* __restrict__ w1,
                                             const float* __restrict__ b1,
                                             const float* __restrict__ w2,
                                             const float* __restrict__ b2,
                                             float* __restrict__ out) {
    __shared__ float g[64][64];
    __shared__ float h[64][64];
    __shared__ float wT[64][65];
    int t = threadIdx.x;
    for (int idx = t; idx < 4096; idx += 256) {
        int gi = idx >> 6, c = idx & 63;
        float cntf = fmaxf((float)g_cnt[gi], 1.f);
        g[gi][c] = g_sum[idx] / cntf;
    }
    for (int idx = t; idx < 4096; idx += 256) {
        int c = idx >> 6, k = idx & 63;
        wT[k][c] = w1[c * 64 + k];
    }
    __syncthreads();
    for (int idx = t; idx < 4096; idx += 256) {
        int gi = idx >> 6, c = idx & 63;
        float acc = b1[c];
        for (int k = 0; k < 64; ++k) acc += g[gi][k] * wT[k][c];
        h[gi][c] = fmaxf(acc, 0.f);
    }
    __syncthreads();
    for (int idx = t; idx < 64 * NCLASSES; idx += 256) {
        int gi = idx >> 4, c = idx & 15;
        float acc = b2[c];
        for (int k = 0; k < 64; ++k) acc += h[gi][k] * w2[c * 64 + k];
        out[gi * NCLASSES + c] = acc;
    }
}

// ---------------------------------------------------------------------------
extern "C" void kernel_launch(void* const* d_in, const int* in_sizes, int n_in,
                              void* d_out, int out_size, void* d_ws, size_t ws_size,
                              hipStream_t stream) {
    const float* x      = (const float*)d_in[0];
    const int*   ei     = (const int*)d_in[1];
    const int*   batch  = (const int*)d_in[2];
    const float* pre_w  = (const float*)d_in[3];
    const float* pre_b  = (const float*)d_in[4];
    const float* post_w = (const float*)d_in[5];
    const float* post_b = (const float*)d_in[6];
    const float* lin_w  = (const float*)d_in[7];
    const float* lin_b  = (const float*)d_in[8];
    const float* mlp_w1 = (const float*)d_in[9];
    const float* mlp_b1 = (const float*)d_in[10];
    const float* mlp_w2 = (const float*)d_in[11];
    const float* mlp_b2 = (const float*)d_in[12];

    const int* src = ei;
    const int* dst = ei + N_EDGES;

    char* base = (char*)d_ws;
    size_t off = 0;
    auto alloc = [&](size_t bytes) -> void* {
        void* ptr = base + off;
        off += (bytes + 255) & ~(size_t)255;
        return ptr;
    };
    int*   cnt       = (int*)alloc(N_NODES * 4);
    int*   row_start = (int*)alloc((N_NODES + 1) * 4);
    int*   cursor    = (int*)alloc(N_NODES * 4);
    int*   csr_src   = (int*)alloc(N_EDGES * 4);
    int*   bsum      = (int*)alloc(64 * 4);
    int*   boff      = (int*)alloc(64 * 4);
    float* logsum    = (float*)alloc(16);
    float* inv_deg   = (float*)alloc(N_NODES * 4);
    float* ampv      = (float*)alloc(N_NODES * 4);
    float* attv      = (float*)alloc(N_NODES * 4);
    float* p         = (float*)alloc((size_t)N_NODES * 64 * 4);
    float* q         = (float*)alloc((size_t)N_NODES * 64 * 4);
    float* aggr      = (float*)alloc((size_t)N_NODES * 256 * 4);
    float* xb0       = (float*)alloc((size_t)N_NODES * 64 * 4);
    float* xb1       = (float*)alloc((size_t)N_NODES * 64 * 4);
    float* g_sum     = (float*)alloc(64 * 64 * 4);
    int*   g_cnt     = (int*)alloc(64 * 4);
    u16*   WkS       = (u16*)alloc((size_t)3 * WKS_LAYER * 2);
    float* bcv       = (float*)alloc(3 * 64 * 4);

    // weight folding (pre-split bf16, frag-ordered, K-permuted) + zero-init
    k_comb<<<625, 256, 0, stream>>>(post_w, lin_w, post_b, lin_b, WkS, bcv,
                                    cnt, logsum);

    k_count<<<(N_EDGES + 255) / 256, 256, 0, stream>>>(dst, cnt);
    k_chunk_sums<<<NCHUNKS, 256, 0, stream>>>(cnt, bsum, logsum);
    k_scan_top<<<1, 64, 0, stream>>>(bsum, boff, row_start);
    k_scan_chunks<<<NCHUNKS, 256, 0, stream>>>(cnt, boff, row_start, cursor);
    k_scatter<<<(N_EDGES + 255) / 256, 256, 0, stream>>>(src, dst, cursor, csr_src);
    k_scal<<<(N_NODES + 255) / 256, 256, 0, stream>>>(cnt, logsum, inv_deg,
                                                      ampv, attv, g_sum, g_cnt);

    const int GEMM_BLOCKS = (N_NODES + 63) / 64;   // 782
    const float* xin = x;
    float* bufs[3] = {xb0, xb1, xb0};
    for (int l = 0; l < NLAYERS; ++l) {
        k_pre<<<GEMM_BLOCKS, 256, 0, stream>>>(xin, pre_w + (size_t)l * 64 * 128,
                                               pre_b + l * 64, p, q);
        k_aggr<<<(N_NODES + 3) / 4, 256, 0, stream>>>(p, q, row_start, csr_src,
                                                      inv_deg, aggr);
        float* xo = bufs[l];
        k_post<<<GEMM_BLOCKS, 256, 0, stream>>>(xin, aggr, ampv, attv,
                                                WkS + (size_t)l * WKS_LAYER,
                                                bcv + l * 64, xo);
        xin = xo;
    }

    int pool_waves = (N_NODES + 127) / 128;
    k_pool<<<(pool_waves + 3) / 4, 256, 0, stream>>>(xin, batch, g_sum, g_cnt);
    k_mlp<<<1, 256, 0, stream>>>(g_sum, g_cnt, mlp_w1, mlp_b1, mlp_w2, mlp_b2,
                                 (float*)d_out);
}

// Round 10
// 492.447 us; speedup vs baseline: 1.4579x; 1.1292x over previous
//
#include <hip/hip_runtime.h>
#include <math.h>

#define N_NODES   50000
#define N_EDGES   800000
#define NUM_GRAPHS 64
#define FDIM      64
#define HDIM      64
#define NLAYERS   3
#define NCLASSES  16
#define EPS       1e-5f

#define SCAN_CHUNK 1024
#define NCHUNKS ((N_NODES + SCAN_CHUNK - 1) / SCAN_CHUNK)   // 49

typedef unsigned short u16;
typedef unsigned int   u32;
typedef __attribute__((ext_vector_type(8))) short short8;   // 8 bf16 (4 VGPRs)
typedef __attribute__((ext_vector_type(4))) float floatx4;  // MFMA accum

// WkS layout per layer (u16 bf16 bits):
//   [26 kchunk][3 split][4 ntile][16 n][32 k-swizzled] -> 159744 u16 per layer
// K-order: chunks 0-1 = x cols 0..63; then for aggr group j (j=0..7, 32 cols):
//   chunk 2+3j+0 = plain, +1 = amp, +2 = att.
// k position within a chunk row is swizzled: element (n16, kin=qh*8+jj) stored
// at n16*32 + ((qh + (n16>>1)) & 3)*8 + jj   (2-way LDS bank spread on read).
#define WKS_LAYER 159744

// ---------------------------------------------------------------------------
__device__ inline void split1(float f, u16& h, u16& m, u16& l) {
    u32 b  = __float_as_uint(f);
    u32 hb = b & 0xFFFF0000u;
    float r = f - __uint_as_float(hb);
    u32 mb = __float_as_uint(r) & 0xFFFF0000u;
    float r2 = r - __uint_as_float(mb);
    u32 lb = __float_as_uint(r2) & 0xFFFF0000u;
    h = (u16)(hb >> 16); m = (u16)(mb >> 16); l = (u16)(lb >> 16);
}

// async global->LDS DMA, 16B per lane (dest = wave-uniform base + lane*16)
__device__ inline void gl_lds16(const void* g, void* l) {
    __builtin_amdgcn_global_load_lds(
        (const __attribute__((address_space(1))) u32*)g,
        (__attribute__((address_space(3))) u32*)l, 16, 0, 0);
}

// ---------------------------------------------------------------------------
// Weight folding Wk = (lin_w @ post_w) -> 3-way bf16 split, frag-ordered with
// the K permutation + swizzle described above; bc = lin_b + lin_w@post_b;
// zero-inits cnt/logsum.
__global__ __launch_bounds__(256) void k_comb(const float* __restrict__ post_w,
                                              const float* __restrict__ lin_w,
                                              const float* __restrict__ post_b,
                                              const float* __restrict__ lin_b,
                                              u16* __restrict__ WkS,
                                              float* __restrict__ bcv,
                                              int* __restrict__ cnt,
                                              float* __restrict__ logsum) {
    int b = blockIdx.x, t = threadIdx.x;
    int zi = b * 256 + t;
    if (zi < N_NODES) cnt[zi] = 0;
    if (zi == 0) *logsum = 0.f;

    if (b < 624) {
        int c  = t & 63;
        int kl = t >> 6;
        int l  = b / 208;
        int o  = (b % 208) * 4 + kl;          // original K column in [0,832)
        const float* lw = lin_w + (size_t)l * 4096 + c * 64;
        const float* pw = post_w + (size_t)l * 53248 + o;
        float acc = 0.f;
        #pragma unroll 8
        for (int j = 0; j < 64; ++j)
            acc += lw[j] * pw[(size_t)j * 832];
        u16 h, m, lo;
        split1(acc, h, m, lo);

        // K permutation: o -> kn
        int kn;
        if (o < 64) kn = o;
        else {
            int s  = (o - 64) >> 8;           // 0 plain, 1 amp, 2 att
            int mm = (o - 64) & 255;          // aggr element index
            int j  = mm >> 5, r = mm & 31;
            kn = 64 + j * 96 + s * 32 + r;
        }
        int ch  = kn >> 5;
        int kin = kn & 31;
        int n16 = c & 15, nt = c >> 4;
        int swk = (((kin >> 3) + (n16 >> 1)) & 3) * 8 + (kin & 7);
        size_t base = (size_t)l * WKS_LAYER + (size_t)ch * 6144
                    + nt * 512 + n16 * 32 + swk;
        WkS[base]        = h;
        WkS[base + 2048] = m;
        WkS[base + 4096] = lo;
    } else if (t < 192) {
        int l = t >> 6, c = t & 63;
        float acc = lin_b[l * 64 + c];
        for (int j = 0; j < 64; ++j)
            acc += lin_w[(size_t)l * 4096 + c * 64 + j] * post_b[l * 64 + j];
        bcv[l * 64 + c] = acc;
    }
}

// ---------------------------------------------------------------------------
// CSR build: degree histogram + per-edge rank (arrival index within its dst)
__global__ void k_count(const int* __restrict__ dst, int* __restrict__ cnt,
                        int* __restrict__ rank) {
    int e = blockIdx.x * 256 + threadIdx.x;
    if (e < N_EDGES) rank[e] = atomicAdd(&cnt[dst[e]], 1);
}

__global__ void k_chunk_sums(const int* __restrict__ cnt, int* __restrict__ bsum,
                             float* __restrict__ logsum) {
    __shared__ int   ired[256];
    __shared__ float lred[256];
    int b = blockIdx.x, t = threadIdx.x;
    int base = b * SCAN_CHUNK;
    int s = 0; float ls = 0.f;
    for (int i = t; i < SCAN_CHUNK; i += 256) {
        int idx = base + i;
        if (idx < N_NODES) {
            int v = cnt[idx];
            s += v;
            ls += logf((float)v + 1.0f);
        }
    }
    ired[t] = s; lred[t] = ls;
    __syncthreads();
    for (int off = 128; off > 0; off >>= 1) {
        if (t < off) { ired[t] += ired[t + off]; lred[t] += lred[t + off]; }
        __syncthreads();
    }
    if (t == 0) { bsum[b] = ired[0]; atomicAdd(logsum, lred[0]); }
}

__global__ void k_scan_top(const int* __restrict__ bsum, int* __restrict__ boff,
                           int* __restrict__ row_start) {
    if (threadIdx.x == 0) {
        int acc = 0;
        for (int i = 0; i < NCHUNKS; ++i) { boff[i] = acc; acc += bsum[i]; }
        row_start[N_NODES] = acc;
    }
}

__global__ void k_scan_chunks(const int* __restrict__ cnt, const int* __restrict__ boff,
                              int* __restrict__ row_start) {
    __shared__ int tsum[256];
    int b = blockIdx.x, t = threadIdx.x;
    int base = b * SCAN_CHUNK + t * 4;
    int v[4]; int s = 0;
    #pragma unroll
    for (int i = 0; i < 4; ++i) {
        int idx = base + i;
        v[i] = (idx < N_NODES) ? cnt[idx] : 0;
        s += v[i];
    }
    tsum[t] = s;
    __syncthreads();
    for (int off = 1; off < 256; off <<= 1) {
        int val = (t >= off) ? tsum[t - off] : 0;
        __syncthreads();
        tsum[t] += val;
        __syncthreads();
    }
    int excl = boff[b] + tsum[t] - s;
    #pragma unroll
    for (int i = 0; i < 4; ++i) {
        int idx = base + i;
        if (idx < N_NODES) row_start[idx] = excl;
        excl += v[i];
    }
}

// atomic-free scatter: slot = row_start[dst] + rank (plain writes, L2-coalesced)
__global__ void k_scatter(const int* __restrict__ src, const int* __restrict__ dst,
                          const int* __restrict__ rank,
                          const int* __restrict__ row_start,
                          int* __restrict__ csr_src) {
    int e = blockIdx.x * 256 + threadIdx.x;
    if (e < N_EDGES) {
        int d = dst[e];
        csr_src[row_start[d] + rank[e]] = src[e];
    }
}

// per-node degree scalers; block 0 also zero-inits pooling accumulators
__global__ void k_scal(const int* __restrict__ cnt, const float* __restrict__ logsum,
                       float* __restrict__ inv_deg, float* __restrict__ ampv,
                       float* __restrict__ attv, float* __restrict__ g_sum,
                       int* __restrict__ g_cnt) {
    int n = blockIdx.x * 256 + threadIdx.x;
    if (blockIdx.x == 0) {
        for (int i = threadIdx.x; i < 4096; i += 256) g_sum[i] = 0.f;
        if (threadIdx.x < 64) g_cnt[threadIdx.x] = 0;
    }
    if (n < N_NODES) {
        float avg = logsum[0] / (float)N_NODES;
        float degf = fmaxf((float)cnt[n], 1.0f);
        inv_deg[n] = 1.0f / degf;
        float ld = logf(degf + 1.0f);
        ampv[n] = ld / avg;
        attv[n] = avg / ld;
    }
}

// ---------------------------------------------------------------------------
// p = x @ Wi^T + pre_b ; q = x @ Wj^T  (unchanged, passing r6 version)
__global__ __launch_bounds__(256) void k_pre(const float* __restrict__ x,
                                             const float* __restrict__ pre_w,
                                             const float* __restrict__ pre_b,
                                             float* __restrict__ p,
                                             float* __restrict__ q) {
    __shared__ float At[64][68];
    __shared__ float Wt[128][68];
    int t = threadIdx.x;
    int c4 = (t & 15) * 4;
    int r4 = (t >> 4) * 4;
    int rowBase = blockIdx.x * 64;
    int srow = t >> 2, skq = t & 3;

    #pragma unroll
    for (int pass = 0; pass < 4; ++pass) {
        int kk = (pass * 4 + skq) * 4;
        int row = rowBase + srow;
        float4 v = make_float4(0.f, 0.f, 0.f, 0.f);
        if (row < N_NODES) v = *(const float4*)&x[(size_t)row * 64 + kk];
        At[kk + 0][srow] = v.x;
        At[kk + 1][srow] = v.y;
        At[kk + 2][srow] = v.z;
        At[kk + 3][srow] = v.w;
    }
    for (int idx4 = t; idx4 < 2048; idx4 += 256) {
        int c = idx4 & 63, kq = idx4 >> 6;
        float4 v = *(const float4*)&pre_w[(size_t)c * 128 + kq * 4];
        Wt[kq * 4 + 0][c] = v.x;
        Wt[kq * 4 + 1][c] = v.y;
        Wt[kq * 4 + 2][c] = v.z;
        Wt[kq * 4 + 3][c] = v.w;
    }
    __syncthreads();

    float accp[4][4] = {{0}}, accq[4][4] = {{0}};
    #pragma unroll 4
    for (int kk = 0; kk < 64; ++kk) {
        float4 a  = *(const float4*)&At[kk][r4];
        float4 wp = *(const float4*)&Wt[kk][c4];
        float4 wq = *(const float4*)&Wt[64 + kk][c4];
        float av[4]  = {a.x, a.y, a.z, a.w};
        float wpv[4] = {wp.x, wp.y, wp.z, wp.w};
        float wqv[4] = {wq.x, wq.y, wq.z, wq.w};
        #pragma unroll
        for (int i = 0; i < 4; ++i)
            #pragma unroll
            for (int j = 0; j < 4; ++j) {
                accp[i][j] += av[i] * wpv[j];
                accq[i][j] += av[i] * wqv[j];
            }
    }
    float pb[4];
    #pragma unroll
    for (int j = 0; j < 4; ++j) pb[j] = pre_b[c4 + j];
    #pragma unroll
    for (int i = 0; i < 4; ++i) {
        int row = rowBase + r4 + i;
        if (row < N_NODES) {
            float4 vp = make_float4(accp[i][0] + pb[0], accp[i][1] + pb[1],
                                    accp[i][2] + pb[2], accp[i][3] + pb[3]);
            float4 vq = make_float4(accq[i][0], accq[i][1], accq[i][2], accq[i][3]);
            *(float4*)&p[row * 64 + c4] = vp;
            *(float4*)&q[row * 64 + c4] = vq;
        }
    }
}

// ---------------------------------------------------------------------------
// Aggregation (unchanged, passing r6 version)
__global__ __launch_bounds__(256) void k_aggr(const float* __restrict__ p,
                                              const float* __restrict__ q,
                                              const int* __restrict__ row_start,
                                              const int* __restrict__ csr_src,
                                              const float* __restrict__ inv_deg,
                                              float* __restrict__ aggr) {
    int wid  = (blockIdx.x * 256 + threadIdx.x) >> 6;
    int lane = threadIdx.x & 63;
    if (wid >= N_NODES) return;
    int n = wid;
    int beg = row_start[n], end = row_start[n + 1];
    float sum = 0.f, sq = 0.f;
    float mn = INFINITY, mx = -INFINITY;
    int e = beg;
    for (; e + 7 < end; e += 8) {
        float qv[8];
        #pragma unroll
        for (int u = 0; u < 8; ++u) {
            int s = csr_src[e + u];
            qv[u] = q[(size_t)s * 64 + lane];
        }
        #pragma unroll
        for (int u = 0; u < 8; ++u) {
            float m = qv[u];
            sum += m; sq += m * m;
            mn = fminf(mn, m); mx = fmaxf(mx, m);
        }
    }
    for (; e + 3 < end; e += 4) {
        float qv[4];
        #pragma unroll
        for (int u = 0; u < 4; ++u) {
            int s = csr_src[e + u];
            qv[u] = q[(size_t)s * 64 + lane];
        }
        #pragma unroll
        for (int u = 0; u < 4; ++u) {
            float m = qv[u];
            sum += m; sq += m * m;
            mn = fminf(mn, m); mx = fmaxf(mx, m);
        }
    }
    for (; e < end; ++e) {
        int s = csr_src[e];
        float m = q[(size_t)s * 64 + lane];
        sum += m; sq += m * m;
        mn = fminf(mn, m); mx = fmaxf(mx, m);
    }
    float* a = aggr + (size_t)n * 256;
    if (end <= beg) {
        a[lane]       = 0.f;
        a[64 + lane]  = 0.f;
        a[128 + lane] = 0.f;
        a[192 + lane] = sqrtf(EPS);
    } else {
        float pv = p[n * 64 + lane];
        float id = inv_deg[n];
        float meanq = sum * id;
        float var = fmaxf(sq * id - meanq * meanq, 0.f);
        a[lane]       = pv + meanq;
        a[64 + lane]  = pv + mn;
        a[128 + lane] = pv + mx;
        a[192 + lane] = sqrtf(var + EPS);
    }
}

// ---------------------------------------------------------------------------
// MFMA k_post v3 (unchanged, passing r9 version): async DMA B-staging,
// 6-MFMA exact 3-way bf16 split.
__global__ __launch_bounds__(256, 4) void k_post(const float* __restrict__ x,
                                                 const float* __restrict__ aggr,
                                                 const float* __restrict__ ampv,
                                                 const float* __restrict__ attv,
                                                 const u16* __restrict__ WkS,
                                                 const float* __restrict__ bc,
                                                 float* __restrict__ xout) {
    __shared__ u16 ldsB[2 * 6144];
    int t = threadIdx.x;
    int w = t >> 6;
    int lane = t & 63;
    int m = lane & 15;
    int qh = lane >> 4;
    int rowBase = blockIdx.x * 64;

    int myrow = rowBase + 16 * w + m;
    bool vr = myrow < N_NODES;
    float ampR = vr ? ampv[myrow] : 0.f;
    float attR = vr ? attv[myrow] : 0.f;
    const float* xrow = x + (size_t)(vr ? myrow : 0) * 64;
    const float* arow = aggr + (size_t)(vr ? myrow : 0) * 256;

    // swizzled B-fragment lane offset within a [16 n][32 k] u16 tile
    int bo = m * 32 + ((qh + (m >> 1)) & 3) * 8;

    floatx4 acc[4] = {};
    float fc[8], fn[8];
    #pragma unroll
    for (int i = 0; i < 8; ++i) { fc[i] = 0.f; fn[i] = 0.f; }

    auto stageIssue = [&](int ch, int buf) {
        const char* g = (const char*)WkS + (size_t)ch * 12288 + w * 3072 + lane * 16;
        char* l = (char*)ldsB + buf * 12288 + w * 3072;   // wave-uniform base
        #pragma unroll
        for (int i = 0; i < 3; ++i)
            gl_lds16(g + i * 1024, l + i * 1024);
    };
    auto loadRaw = [&](const float* sp, float* f) {   // 32B contiguous
        if (!vr) {
            #pragma unroll
            for (int i = 0; i < 8; ++i) f[i] = 0.f;
            return;
        }
        float4 u0 = *(const float4*)sp;
        float4 u1 = *(const float4*)(sp + 4);
        f[0] = u0.x; f[1] = u0.y; f[2] = u0.z; f[3] = u0.w;
        f[4] = u1.x; f[5] = u1.y; f[6] = u1.z; f[7] = u1.w;
    };

    stageIssue(0, 0);
    loadRaw(xrow + qh * 8, fc);
    asm volatile("s_waitcnt vmcnt(0)" ::: "memory");
    __syncthreads();

    for (int ch = 0; ch < 26; ++ch) {
        if (ch + 1 < 26) stageIssue(ch + 1, (ch + 1) & 1);

        if (ch == 0)      loadRaw(xrow + 32 + qh * 8, fn);
        else if (ch == 1) loadRaw(arow + qh * 8, fn);
        else {
            int j = (ch - 2) / 3, s = (ch - 2) % 3;
            if (s == 2 && j < 7) loadRaw(arow + (j + 1) * 32 + qh * 8, fn);
        }

        float sc = 1.f;
        if (ch >= 2) {
            int s = (ch - 2) % 3;
            sc = (s == 0) ? 1.f : ((s == 1) ? ampR : attR);
        }

        union { u32 u[4]; short8 s8; } AH, AM, AL;
        #pragma unroll
        for (int i = 0; i < 4; ++i) {
            float f0 = fc[2 * i] * sc, f1 = fc[2 * i + 1] * sc;
            u32 b0 = __float_as_uint(f0), b1 = __float_as_uint(f1);
            u32 h0 = b0 & 0xFFFF0000u,  h1 = b1 & 0xFFFF0000u;
            float r0 = f0 - __uint_as_float(h0);
            float r1 = f1 - __uint_as_float(h1);
            u32 m0 = __float_as_uint(r0) & 0xFFFF0000u;
            u32 m1 = __float_as_uint(r1) & 0xFFFF0000u;
            float s0 = r0 - __uint_as_float(m0);
            float s1 = r1 - __uint_as_float(m1);
            u32 l0 = __float_as_uint(s0) & 0xFFFF0000u;
            u32 l1 = __float_as_uint(s1) & 0xFFFF0000u;
            AH.u[i] = (h0 >> 16) | h1;
            AM.u[i] = (m0 >> 16) | m1;
            AL.u[i] = (l0 >> 16) | l1;
        }

        const u16* Bb = ldsB + (ch & 1) * 6144;
        #pragma unroll
        for (int nt = 0; nt < 4; ++nt) {
            short8 bH = *(const short8*)(Bb + nt * 512 + bo);
            short8 bM = *(const short8*)(Bb + 2048 + nt * 512 + bo);
            short8 bL = *(const short8*)(Bb + 4096 + nt * 512 + bo);
            acc[nt] = __builtin_amdgcn_mfma_f32_16x16x32_bf16(AH.s8, bH, acc[nt], 0, 0, 0);
            acc[nt] = __builtin_amdgcn_mfma_f32_16x16x32_bf16(AH.s8, bM, acc[nt], 0, 0, 0);
            acc[nt] = __builtin_amdgcn_mfma_f32_16x16x32_bf16(AM.s8, bH, acc[nt], 0, 0, 0);
            acc[nt] = __builtin_amdgcn_mfma_f32_16x16x32_bf16(AH.s8, bL, acc[nt], 0, 0, 0);
            acc[nt] = __builtin_amdgcn_mfma_f32_16x16x32_bf16(AM.s8, bM, acc[nt], 0, 0, 0);
            acc[nt] = __builtin_amdgcn_mfma_f32_16x16x32_bf16(AL.s8, bH, acc[nt], 0, 0, 0);
        }

        asm volatile("s_waitcnt vmcnt(0)" ::: "memory");
        __syncthreads();

        bool adv = (ch < 2) || ((ch - 2) % 3 == 2);
        if (adv) {
            #pragma unroll
            for (int i = 0; i < 8; ++i) fc[i] = fn[i];
        }
    }

    int col = lane & 15;
    #pragma unroll
    for (int nt = 0; nt < 4; ++nt) {
        float bias = bc[nt * 16 + col];
        #pragma unroll
        for (int reg = 0; reg < 4; ++reg) {
            int grow = rowBase + 16 * w + qh * 4 + reg;
            if (grow < N_NODES) {
                xout[(size_t)grow * 64 + nt * 16 + col] =
                    fmaxf(acc[nt][reg] + bias, 0.f);
            }
        }
    }
}

// ---------------------------------------------------------------------------
// Mean pooling: 16 nodes per wave (3125 waves) -> latency hidden by TLP;
// batch sorted so each slab spans ~1-2 graphs => ~2 atomic flushes per wave.
__global__ __launch_bounds__(256) void k_pool(const float* __restrict__ x,
                                              const int* __restrict__ batch,
                                              float* __restrict__ g_sum,
                                              int* __restrict__ g_cnt) {
    int lane = threadIdx.x & 63;
    int wave = blockIdx.x * 4 + (threadIdx.x >> 6);
    const int NPW = 16;
    int beg = wave * NPW;
    if (beg >= N_NODES) return;
    int end = min(beg + NPW, N_NODES);
    float acc = 0.f;
    int cur = batch[beg];
    int c = 0;
    for (int n = beg; n < end; ++n) {
        int b = batch[n];
        if (b != cur) {
            atomicAdd(&g_sum[cur * 64 + lane], acc);
            if (lane == 0) atomicAdd(&g_cnt[cur], c);
            acc = 0.f; c = 0; cur = b;
        }
        acc += x[n * 64 + lane];
        ++c;
    }
    atomicAdd(&g_sum[cur * 64 + lane], acc);
    if (lane == 0) atomicAdd(&g_cnt[cur], c);
}

__global__ __launch_bounds__(256) void k_mlp(const float* __restrict__ g_sum,
                                             const int* __restrict__ g_cnt,
                                             const float* __restrict__ w1,
                                             const float* __restrict__ b1,
                                             const float* __restrict__ w2,
                                             const float* __restrict__ b2,
                                             float* __restrict__ out) {
    __shared__ float g[64][64];
    __shared__ float h[64][64];
    __shared__ float wT[64][65];
    int t = threadIdx.x;
    for (int idx = t; idx < 4096; idx += 256) {
        int gi = idx >> 6, c = idx & 63;
        float cntf = fmaxf((float)g_cnt[gi], 1.f);
        g[gi][c] = g_sum[idx] / cntf;
    }
    for (int idx = t; idx < 4096; idx += 256) {
        int c = idx >> 6, k = idx & 63;
        wT[k][c] = w1[c * 64 + k];
    }
    __syncthreads();
    for (int idx = t; idx < 4096; idx += 256) {
        int gi = idx >> 6, c = idx & 63;
        float acc = b1[c];
        for (int k = 0; k < 64; ++k) acc += g[gi][k] * wT[k][c];
        h[gi][c] = fmaxf(acc, 0.f);
    }
    __syncthreads();
    for (int idx = t; idx < 64 * NCLASSES; idx += 256) {
        int gi = idx >> 4, c = idx & 15;
        float acc = b2[c];
        for (int k = 0; k < 64; ++k) acc += h[gi][k] * w2[c * 64 + k];
        out[gi * NCLASSES + c] = acc;
    }
}

// ---------------------------------------------------------------------------
extern "C" void kernel_launch(void* const* d_in, const int* in_sizes, int n_in,
                              void* d_out, int out_size, void* d_ws, size_t ws_size,
                              hipStream_t stream) {
    const float* x      = (const float*)d_in[0];
    const int*   ei     = (const int*)d_in[1];
    const int*   batch  = (const int*)d_in[2];
    const float* pre_w  = (const float*)d_in[3];
    const float* pre_b  = (const float*)d_in[4];
    const float* post_w = (const float*)d_in[5];
    const float* post_b = (const float*)d_in[6];
    const float* lin_w  = (const float*)d_in[7];
    const float* lin_b  = (const float*)d_in[8];
    const float* mlp_w1 = (const float*)d_in[9];
    const float* mlp_b1 = (const float*)d_in[10];
    const float* mlp_w2 = (const float*)d_in[11];
    const float* mlp_b2 = (const float*)d_in[12];

    const int* src = ei;
    const int* dst = ei + N_EDGES;

    char* base = (char*)d_ws;
    size_t off = 0;
    auto alloc = [&](size_t bytes) -> void* {
        void* ptr = base + off;
        off += (bytes + 255) & ~(size_t)255;
        return ptr;
    };
    int*   cnt       = (int*)alloc(N_NODES * 4);
    int*   row_start = (int*)alloc((N_NODES + 1) * 4);
    int*   rank      = (int*)alloc(N_EDGES * 4);
    int*   csr_src   = (int*)alloc(N_EDGES * 4);
    int*   bsum      = (int*)alloc(64 * 4);
    int*   boff      = (int*)alloc(64 * 4);
    float* logsum    = (float*)alloc(16);
    float* inv_deg   = (float*)alloc(N_NODES * 4);
    float* ampv      = (float*)alloc(N_NODES * 4);
    float* attv      = (float*)alloc(N_NODES * 4);
    float* p         = (float*)alloc((size_t)N_NODES * 64 * 4);
    float* q         = (float*)alloc((size_t)N_NODES * 64 * 4);
    float* aggr      = (float*)alloc((size_t)N_NODES * 256 * 4);
    float* xb0       = (float*)alloc((size_t)N_NODES * 64 * 4);
    float* xb1       = (float*)alloc((size_t)N_NODES * 64 * 4);
    float* g_sum     = (float*)alloc(64 * 64 * 4);
    int*   g_cnt     = (int*)alloc(64 * 4);
    u16*   WkS       = (u16*)alloc((size_t)3 * WKS_LAYER * 2);
    float* bcv       = (float*)alloc(3 * 64 * 4);

    // weight folding (pre-split bf16, frag-ordered, K-permuted) + zero-init
    k_comb<<<625, 256, 0, stream>>>(post_w, lin_w, post_b, lin_b, WkS, bcv,
                                    cnt, logsum);

    k_count<<<(N_EDGES + 255) / 256, 256, 0, stream>>>(dst, cnt, rank);
    k_chunk_sums<<<NCHUNKS, 256, 0, stream>>>(cnt, bsum, logsum);
    k_scan_top<<<1, 64, 0, stream>>>(bsum, boff, row_start);
    k_scan_chunks<<<NCHUNKS, 256, 0, stream>>>(cnt, boff, row_start);
    k_scatter<<<(N_EDGES + 255) / 256, 256, 0, stream>>>(src, dst, rank,
                                                         row_start, csr_src);
    k_scal<<<(N_NODES + 255) / 256, 256, 0, stream>>>(cnt, logsum, inv_deg,
                                                      ampv, attv, g_sum, g_cnt);

    const int GEMM_BLOCKS = (N_NODES + 63) / 64;   // 782
    const float* xin = x;
    float* bufs[3] = {xb0, xb1, xb0};
    for (int l = 0; l < NLAYERS; ++l) {
        k_pre<<<GEMM_BLOCKS, 256, 0, stream>>>(xin, pre_w + (size_t)l * 64 * 128,
                                               pre_b + l * 64, p, q);
        k_aggr<<<(N_NODES + 3) / 4, 256, 0, stream>>>(p, q, row_start, csr_src,
                                                      inv_deg, aggr);
        float* xo = bufs[l];
        k_post<<<GEMM_BLOCKS, 256, 0, stream>>>(xin, aggr, ampv, attv,
                                                WkS + (size_t)l * WKS_LAYER,
                                                bcv + l * 64, xo);
        xin = xo;
    }

    int pool_waves = (N_NODES + 15) / 16;
    k_pool<<<(pool_waves + 3) / 4, 256, 0, stream>>>(xin, batch, g_sum, g_cnt);
    k_mlp<<<1, 256, 0, stream>>>(g_sum, g_cnt, mlp_w1, mlp_b1, mlp_w2, mlp_b2,
                                 (float*)d_out);
}

// Round 11
// 491.514 us; speedup vs baseline: 1.4607x; 1.0019x over previous
//
#include <hip/hip_runtime.h>
#include <math.h>

#define N_NODES   50000
#define N_EDGES   800000
#define NUM_GRAPHS 64
#define FDIM      64
#define HDIM      64
#define NLAYERS   3
#define NCLASSES  16
#define EPS       1e-5f

#define SCAN_CHUNK 1024
#define NCHUNKS ((N_NODES + SCAN_CHUNK - 1) / SCAN_CHUNK)   // 49

typedef unsigned short u16;
typedef unsigned int   u32;
typedef __attribute__((ext_vector_type(8))) short short8;   // 8 bf16 (4 VGPRs)
typedef __attribute__((ext_vector_type(4))) float floatx4;  // MFMA accum

// WkS layout per layer (u16 bf16 bits):
//   [26 kchunk][3 split][4 ntile][16 n][32 k-swizzled] -> 159744 u16 per layer
// K-order: chunks 0-1 = x cols 0..63; then for aggr group j (j=0..7, 32 cols):
//   chunk 2+3j+0 = plain, +1 = amp, +2 = att.
// k position within a chunk row is swizzled: element (n16, kin=qh*8+jj) stored
// at n16*32 + ((qh + (n16>>1)) & 3)*8 + jj   (2-way LDS bank spread on read).
#define WKS_LAYER 159744

// ---------------------------------------------------------------------------
__device__ inline void split1(float f, u16& h, u16& m, u16& l) {
    u32 b  = __float_as_uint(f);
    u32 hb = b & 0xFFFF0000u;
    float r = f - __uint_as_float(hb);
    u32 mb = __float_as_uint(r) & 0xFFFF0000u;
    float r2 = r - __uint_as_float(mb);
    u32 lb = __float_as_uint(r2) & 0xFFFF0000u;
    h = (u16)(hb >> 16); m = (u16)(mb >> 16); l = (u16)(lb >> 16);
}

// async global->LDS DMA, 16B per lane (dest = wave-uniform base + lane*16)
__device__ inline void gl_lds16(const void* g, void* l) {
    __builtin_amdgcn_global_load_lds(
        (const __attribute__((address_space(1))) u32*)g,
        (__attribute__((address_space(3))) u32*)l, 16, 0, 0);
}

// ---------------------------------------------------------------------------
// Weight folding Wk = (lin_w @ post_w) -> 3-way bf16 split, frag-ordered with
// the K permutation + swizzle described above; bc = lin_b + lin_w@post_b;
// zero-inits cnt/logsum.
__global__ __launch_bounds__(256) void k_comb(const float* __restrict__ post_w,
                                              const float* __restrict__ lin_w,
                                              const float* __restrict__ post_b,
                                              const float* __restrict__ lin_b,
                                              u16* __restrict__ WkS,
                                              float* __restrict__ bcv,
                                              int* __restrict__ cnt,
                                              float* __restrict__ logsum) {
    int b = blockIdx.x, t = threadIdx.x;
    int zi = b * 256 + t;
    if (zi < N_NODES) cnt[zi] = 0;
    if (zi == 0) *logsum = 0.f;

    if (b < 624) {
        int c  = t & 63;
        int kl = t >> 6;
        int l  = b / 208;
        int o  = (b % 208) * 4 + kl;          // original K column in [0,832)
        const float* lw = lin_w + (size_t)l * 4096 + c * 64;
        const float* pw = post_w + (size_t)l * 53248 + o;
        float acc = 0.f;
        #pragma unroll 8
        for (int j = 0; j < 64; ++j)
            acc += lw[j] * pw[(size_t)j * 832];
        u16 h, m, lo;
        split1(acc, h, m, lo);

        // K permutation: o -> kn
        int kn;
        if (o < 64) kn = o;
        else {
            int s  = (o - 64) >> 8;           // 0 plain, 1 amp, 2 att
            int mm = (o - 64) & 255;          // aggr element index
            int j  = mm >> 5, r = mm & 31;
            kn = 64 + j * 96 + s * 32 + r;
        }
        int ch  = kn >> 5;
        int kin = kn & 31;
        int n16 = c & 15, nt = c >> 4;
        int swk = (((kin >> 3) + (n16 >> 1)) & 3) * 8 + (kin & 7);
        size_t base = (size_t)l * WKS_LAYER + (size_t)ch * 6144
                    + nt * 512 + n16 * 32 + swk;
        WkS[base]        = h;
        WkS[base + 2048] = m;
        WkS[base + 4096] = lo;
    } else if (t < 192) {
        int l = t >> 6, c = t & 63;
        float acc = lin_b[l * 64 + c];
        for (int j = 0; j < 64; ++j)
            acc += lin_w[(size_t)l * 4096 + c * 64 + j] * post_b[l * 64 + j];
        bcv[l * 64 + c] = acc;
    }
}

// ---------------------------------------------------------------------------
// CSR build: degree histogram + per-edge rank (arrival index within its dst)
__global__ void k_count(const int* __restrict__ dst, int* __restrict__ cnt,
                        int* __restrict__ rank) {
    int e = blockIdx.x * 256 + threadIdx.x;
    if (e < N_EDGES) rank[e] = atomicAdd(&cnt[dst[e]], 1);
}

__global__ void k_chunk_sums(const int* __restrict__ cnt, int* __restrict__ bsum,
                             float* __restrict__ logsum) {
    __shared__ int   ired[256];
    __shared__ float lred[256];
    int b = blockIdx.x, t = threadIdx.x;
    int base = b * SCAN_CHUNK;
    int s = 0; float ls = 0.f;
    for (int i = t; i < SCAN_CHUNK; i += 256) {
        int idx = base + i;
        if (idx < N_NODES) {
            int v = cnt[idx];
            s += v;
            ls += logf((float)v + 1.0f);
        }
    }
    ired[t] = s; lred[t] = ls;
    __syncthreads();
    for (int off = 128; off > 0; off >>= 1) {
        if (t < off) { ired[t] += ired[t + off]; lred[t] += lred[t + off]; }
        __syncthreads();
    }
    if (t == 0) { bsum[b] = ired[0]; atomicAdd(logsum, lred[0]); }
}

__global__ void k_scan_top(const int* __restrict__ bsum, int* __restrict__ boff,
                           int* __restrict__ row_start) {
    if (threadIdx.x == 0) {
        int acc = 0;
        for (int i = 0; i < NCHUNKS; ++i) { boff[i] = acc; acc += bsum[i]; }
        row_start[N_NODES] = acc;
    }
}

__global__ void k_scan_chunks(const int* __restrict__ cnt, const int* __restrict__ boff,
                              int* __restrict__ row_start) {
    __shared__ int tsum[256];
    int b = blockIdx.x, t = threadIdx.x;
    int base = b * SCAN_CHUNK + t * 4;
    int v[4]; int s = 0;
    #pragma unroll
    for (int i = 0; i < 4; ++i) {
        int idx = base + i;
        v[i] = (idx < N_NODES) ? cnt[idx] : 0;
        s += v[i];
    }
    tsum[t] = s;
    __syncthreads();
    for (int off = 1; off < 256; off <<= 1) {
        int val = (t >= off) ? tsum[t - off] : 0;
        __syncthreads();
        tsum[t] += val;
        __syncthreads();
    }
    int excl = boff[b] + tsum[t] - s;
    #pragma unroll
    for (int i = 0; i < 4; ++i) {
        int idx = base + i;
        if (idx < N_NODES) row_start[idx] = excl;
        excl += v[i];
    }
}

// atomic-free scatter: slot = row_start[dst] + rank (plain writes, L2-coalesced)
__global__ void k_scatter(const int* __restrict__ src, const int* __restrict__ dst,
                          const int* __restrict__ rank,
                          const int* __restrict__ row_start,
                          int* __restrict__ csr_src) {
    int e = blockIdx.x * 256 + threadIdx.x;
    if (e < N_EDGES) {
        int d = dst[e];
        csr_src[row_start[d] + rank[e]] = src[e];
    }
}

// per-node degree scalers; block 0 also zero-inits pooling accumulators
__global__ void k_scal(const int* __restrict__ cnt, const float* __restrict__ logsum,
                       float* __restrict__ inv_deg, float* __restrict__ ampv,
                       float* __restrict__ attv, float* __restrict__ g_sum,
                       int* __restrict__ g_cnt) {
    int n = blockIdx.x * 256 + threadIdx.x;
    if (blockIdx.x == 0) {
        for (int i = threadIdx.x; i < 4096; i += 256) g_sum[i] = 0.f;
        if (threadIdx.x < 64) g_cnt[threadIdx.x] = 0;
    }
    if (n < N_NODES) {
        float avg = logsum[0] / (float)N_NODES;
        float degf = fmaxf((float)cnt[n], 1.0f);
        inv_deg[n] = 1.0f / degf;
        float ld = logf(degf + 1.0f);
        ampv[n] = ld / avg;
        attv[n] = avg / ld;
    }
}

// ---------------------------------------------------------------------------
// p = x @ Wi^T + pre_b ; q = x @ Wj^T  (unchanged, passing r6 version)
__global__ __launch_bounds__(256) void k_pre(const float* __restrict__ x,
                                             const float* __restrict__ pre_w,
                                             const float* __restrict__ pre_b,
                                             float* __restrict__ p,
                                             float* __restrict__ q) {
    __shared__ float At[64][68];
    __shared__ float Wt[128][68];
    int t = threadIdx.x;
    int c4 = (t & 15) * 4;
    int r4 = (t >> 4) * 4;
    int rowBase = blockIdx.x * 64;
    int srow = t >> 2, skq = t & 3;

    #pragma unroll
    for (int pass = 0; pass < 4; ++pass) {
        int kk = (pass * 4 + skq) * 4;
        int row = rowBase + srow;
        float4 v = make_float4(0.f, 0.f, 0.f, 0.f);
        if (row < N_NODES) v = *(const float4*)&x[(size_t)row * 64 + kk];
        At[kk + 0][srow] = v.x;
        At[kk + 1][srow] = v.y;
        At[kk + 2][srow] = v.z;
        At[kk + 3][srow] = v.w;
    }
    for (int idx4 = t; idx4 < 2048; idx4 += 256) {
        int c = idx4 & 63, kq = idx4 >> 6;
        float4 v = *(const float4*)&pre_w[(size_t)c * 128 + kq * 4];
        Wt[kq * 4 + 0][c] = v.x;
        Wt[kq * 4 + 1][c] = v.y;
        Wt[kq * 4 + 2][c] = v.z;
        Wt[kq * 4 + 3][c] = v.w;
    }
    __syncthreads();

    float accp[4][4] = {{0}}, accq[4][4] = {{0}};
    #pragma unroll 4
    for (int kk = 0; kk < 64; ++kk) {
        float4 a  = *(const float4*)&At[kk][r4];
        float4 wp = *(const float4*)&Wt[kk][c4];
        float4 wq = *(const float4*)&Wt[64 + kk][c4];
        float av[4]  = {a.x, a.y, a.z, a.w};
        float wpv[4] = {wp.x, wp.y, wp.z, wp.w};
        float wqv[4] = {wq.x, wq.y, wq.z, wq.w};
        #pragma unroll
        for (int i = 0; i < 4; ++i)
            #pragma unroll
            for (int j = 0; j < 4; ++j) {
                accp[i][j] += av[i] * wpv[j];
                accq[i][j] += av[i] * wqv[j];
            }
    }
    float pb[4];
    #pragma unroll
    for (int j = 0; j < 4; ++j) pb[j] = pre_b[c4 + j];
    #pragma unroll
    for (int i = 0; i < 4; ++i) {
        int row = rowBase + r4 + i;
        if (row < N_NODES) {
            float4 vp = make_float4(accp[i][0] + pb[0], accp[i][1] + pb[1],
                                    accp[i][2] + pb[2], accp[i][3] + pb[3]);
            float4 vq = make_float4(accq[i][0], accq[i][1], accq[i][2], accq[i][3]);
            *(float4*)&p[row * 64 + c4] = vp;
            *(float4*)&q[row * 64 + c4] = vq;
        }
    }
}

// ---------------------------------------------------------------------------
// Aggregation (unchanged, passing r6 version)
__global__ __launch_bounds__(256) void k_aggr(const float* __restrict__ p,
                                              const float* __restrict__ q,
                                              const int* __restrict__ row_start,
                                              const int* __restrict__ csr_src,
                                              const float* __restrict__ inv_deg,
                                              float* __restrict__ aggr) {
    int wid  = (blockIdx.x * 256 + threadIdx.x) >> 6;
    int lane = threadIdx.x & 63;
    if (wid >= N_NODES) return;
    int n = wid;
    int beg = row_start[n], end = row_start[n + 1];
    float sum = 0.f, sq = 0.f;
    float mn = INFINITY, mx = -INFINITY;
    int e = beg;
    for (; e + 7 < end; e += 8) {
        float qv[8];
        #pragma unroll
        for (int u = 0; u < 8; ++u) {
            int s = csr_src[e + u];
            qv[u] = q[(size_t)s * 64 + lane];
        }
        #pragma unroll
        for (int u = 0; u < 8; ++u) {
            float m = qv[u];
            sum += m; sq += m * m;
            mn = fminf(mn, m); mx = fmaxf(mx, m);
        }
    }
    for (; e + 3 < end; e += 4) {
        float qv[4];
        #pragma unroll
        for (int u = 0; u < 4; ++u) {
            int s = csr_src[e + u];
            qv[u] = q[(size_t)s * 64 + lane];
        }
        #pragma unroll
        for (int u = 0; u < 4; ++u) {
            float m = qv[u];
            sum += m; sq += m * m;
            mn = fminf(mn, m); mx = fmaxf(mx, m);
        }
    }
    for (; e < end; ++e) {
        int s = csr_src[e];
        float m = q[(size_t)s * 64 + lane];
        sum += m; sq += m * m;
        mn = fminf(mn, m); mx = fmaxf(mx, m);
    }
    float* a = aggr + (size_t)n * 256;
    if (end <= beg) {
        a[lane]       = 0.f;
        a[64 + lane]  = 0.f;
        a[128 + lane] = 0.f;
        a[192 + lane] = sqrtf(EPS);
    } else {
        float pv = p[n * 64 + lane];
        float id = inv_deg[n];
        float meanq = sum * id;
        float var = fmaxf(sq * id - meanq * meanq, 0.f);
        a[lane]       = pv + meanq;
        a[64 + lane]  = pv + mn;
        a[128 + lane] = pv + mx;
        a[192 + lane] = sqrtf(var + EPS);
    }
}

// ---------------------------------------------------------------------------
// MFMA k_post v4: triple-buffered async DMA with fine-grained vmcnt(5) + raw
// s_barrier (prefetch stays in flight across the barrier — no full drain).
// Per iteration, EXACTLY 2 A-loads then 3 DMAs are issued (counts constant,
// loads unconditional via clamped pointers) so the vmcnt immediate is valid.
__global__ __launch_bounds__(256, 4) void k_post(const float* __restrict__ x,
                                                 const float* __restrict__ aggr,
                                                 const float* __restrict__ ampv,
                                                 const float* __restrict__ attv,
                                                 const u16* __restrict__ WkS,
                                                 const float* __restrict__ bc,
                                                 float* __restrict__ xout) {
    __shared__ u16 ldsB[3 * 6144];
    int t = threadIdx.x;
    int w = t >> 6;
    int lane = t & 63;
    int m = lane & 15;
    int qh = lane >> 4;
    int rowBase = blockIdx.x * 64;

    int myrow = rowBase + 16 * w + m;
    bool vr = myrow < N_NODES;
    int crow = vr ? myrow : 0;                 // clamped row (always valid mem)
    float ampR = vr ? ampv[crow] : 0.f;
    float attR = vr ? attv[crow] : 0.f;
    const float* xrow = x + (size_t)crow * 64;
    const float* arow = aggr + (size_t)crow * 256;

    // swizzled B-fragment lane offset within a [16 n][32 k] u16 tile
    int bo = m * 32 + ((qh + (m >> 1)) & 3) * 8;

    floatx4 acc[4] = {};
    float fc[8], fn[8];

    // A-source pointer for a chunk (clamped for ch>=26)
    auto aptr = [&](int ch) -> const float* {
        if (ch <= 0) return xrow;
        if (ch == 1) return xrow + 32;
        int j = (ch - 2) / 3;
        if (j > 7) j = 7;
        return arow + j * 32;
    };
    // unconditional 32B load + per-lane select (no exec-branch: instruction
    // count is identical for fully-OOB waves — required for vmcnt math)
    auto loadRaw = [&](const float* sp, float* f) {
        float4 u0 = *(const float4*)(sp + qh * 8);
        float4 u1 = *(const float4*)(sp + qh * 8 + 4);
        f[0] = vr ? u0.x : 0.f; f[1] = vr ? u0.y : 0.f;
        f[2] = vr ? u0.z : 0.f; f[3] = vr ? u0.w : 0.f;
        f[4] = vr ? u1.x : 0.f; f[5] = vr ? u1.y : 0.f;
        f[6] = vr ? u1.z : 0.f; f[7] = vr ? u1.w : 0.f;
    };
    // 3 async DMAs: wave w copies bytes [3072w, 3072w+3072) of a 12288B chunk
    auto stageIssue = [&](int ch, int buf) {
        const char* g = (const char*)WkS + (size_t)ch * 12288 + w * 3072 + lane * 16;
        char* l = (char*)ldsB + buf * 12288 + w * 3072;
        #pragma unroll
        for (int i = 0; i < 3; ++i)
            gl_lds16(g + i * 1024, l + i * 1024);
    };

    // prologue: A(0) -> fc [2 loads], DMA chunk 0 and 1 [3+3]
    loadRaw(aptr(0), fc);
    stageIssue(0, 0);
    stageIssue(1, 1);
    asm volatile("s_waitcnt vmcnt(3)" ::: "memory");   // A(0)+D(0) done; D(1) in flight
    asm volatile("s_barrier" ::: "memory");

    for (int ch = 0; ch < 26; ++ch) {
        // A for next chunk FIRST (so the fc<-fn wait below leaves DMAs in flight)
        loadRaw(aptr(ch + 1), fn);                      // 2 loads
        int ch2 = (ch + 2 < 26) ? ch + 2 : ch + 2 - 26; // wrap: keeps counts constant
        stageIssue(ch2, (ch + 2) % 3);                  // 3 DMAs

        float sc = 1.f;
        if (ch >= 2) {
            int s = (ch - 2) % 3;
            sc = (s == 0) ? 1.f : ((s == 1) ? ampR : attR);
        }

        // scale + exact 3-way split of fc
        union { u32 u[4]; short8 s8; } AH, AM, AL;
        #pragma unroll
        for (int i = 0; i < 4; ++i) {
            float f0 = fc[2 * i] * sc, f1 = fc[2 * i + 1] * sc;
            u32 b0 = __float_as_uint(f0), b1 = __float_as_uint(f1);
            u32 h0 = b0 & 0xFFFF0000u,  h1 = b1 & 0xFFFF0000u;
            float r0 = f0 - __uint_as_float(h0);
            float r1 = f1 - __uint_as_float(h1);
            u32 m0 = __float_as_uint(r0) & 0xFFFF0000u;
            u32 m1 = __float_as_uint(r1) & 0xFFFF0000u;
            float s0 = r0 - __uint_as_float(m0);
            float s1 = r1 - __uint_as_float(m1);
            u32 l0 = __float_as_uint(s0) & 0xFFFF0000u;
            u32 l1 = __float_as_uint(s1) & 0xFFFF0000u;
            AH.u[i] = (h0 >> 16) | h1;
            AM.u[i] = (m0 >> 16) | m1;
            AL.u[i] = (l0 >> 16) | l1;
        }

        const u16* Bb = ldsB + (ch % 3) * 6144;
        #pragma unroll
        for (int nt = 0; nt < 4; ++nt) {
            short8 bH = *(const short8*)(Bb + nt * 512 + bo);
            short8 bM = *(const short8*)(Bb + 2048 + nt * 512 + bo);
            short8 bL = *(const short8*)(Bb + 4096 + nt * 512 + bo);
            acc[nt] = __builtin_amdgcn_mfma_f32_16x16x32_bf16(AH.s8, bH, acc[nt], 0, 0, 0);
            acc[nt] = __builtin_amdgcn_mfma_f32_16x16x32_bf16(AH.s8, bM, acc[nt], 0, 0, 0);
            acc[nt] = __builtin_amdgcn_mfma_f32_16x16x32_bf16(AM.s8, bH, acc[nt], 0, 0, 0);
            acc[nt] = __builtin_amdgcn_mfma_f32_16x16x32_bf16(AH.s8, bL, acc[nt], 0, 0, 0);
            acc[nt] = __builtin_amdgcn_mfma_f32_16x16x32_bf16(AM.s8, bM, acc[nt], 0, 0, 0);
            acc[nt] = __builtin_amdgcn_mfma_f32_16x16x32_bf16(AL.s8, bH, acc[nt], 0, 0, 0);
        }

        // wait: oldest 3 (= DMA for chunk ch+1) complete; this iteration's
        // 2 A-loads + 3 DMAs (newest 5) stay in flight across the barrier.
        asm volatile("s_waitcnt vmcnt(5)" ::: "memory");
        asm volatile("s_barrier" ::: "memory");

        #pragma unroll
        for (int i = 0; i < 8; ++i) fc[i] = fn[i];   // compiler waits A-loads only
    }

    // epilogue: C/D layout col = lane&15, row = (lane>>4)*4 + reg
    int col = lane & 15;
    #pragma unroll
    for (int nt = 0; nt < 4; ++nt) {
        float bias = bc[nt * 16 + col];
        #pragma unroll
        for (int reg = 0; reg < 4; ++reg) {
            int grow = rowBase + 16 * w + qh * 4 + reg;
            if (grow < N_NODES) {
                xout[(size_t)grow * 64 + nt * 16 + col] =
                    fmaxf(acc[nt][reg] + bias, 0.f);
            }
        }
    }
}

// ---------------------------------------------------------------------------
// Mean pooling: 16 nodes per wave (3125 waves) -> latency hidden by TLP.
__global__ __launch_bounds__(256) void k_pool(const float* __restrict__ x,
                                              const int* __restrict__ batch,
                                              float* __restrict__ g_sum,
                                              int* __restrict__ g_cnt) {
    int lane = threadIdx.x & 63;
    int wave = blockIdx.x * 4 + (threadIdx.x >> 6);
    const int NPW = 16;
    int beg = wave * NPW;
    if (beg >= N_NODES) return;
    int end = min(beg + NPW, N_NODES);
    float acc = 0.f;
    int cur = batch[beg];
    int c = 0;
    for (int n = beg; n < end; ++n) {
        int b = batch[n];
        if (b != cur) {
            atomicAdd(&g_sum[cur * 64 + lane], acc);
            if (lane == 0) atomicAdd(&g_cnt[cur], c);
            acc = 0.f; c = 0; cur = b;
        }
        acc += x[n * 64 + lane];
        ++c;
    }
    atomicAdd(&g_sum[cur * 64 + lane], acc);
    if (lane == 0) atomicAdd(&g_cnt[cur], c);
}

__global__ __launch_bounds__(256) void k_mlp(const float* __restrict__ g_sum,
                                             const int* __restrict__ g_cnt,
                                             const float* __restrict__ w1,
                                             const float* __restrict__ b1,
                                             const float* __restrict__ w2,
                                             const float* __restrict__ b2,
                                             float* __restrict__ out) {
    __shared__ float g[64][64];
    __shared__ float h[64][64];
    __shared__ float wT[64][65];
    int t = threadIdx.x;
    for (int idx = t; idx < 4096; idx += 256) {
        int gi = idx >> 6, c = idx & 63;
        float cntf = fmaxf((float)g_cnt[gi], 1.f);
        g[gi][c] = g_sum[idx] / cntf;
    }
    for (int idx = t; idx < 4096; idx += 256) {
        int c = idx >> 6, k = idx & 63;
        wT[k][c] = w1[c * 64 + k];
    }
    __syncthreads();
    for (int idx = t; idx < 4096; idx += 256) {
        int gi = idx >> 6, c = idx & 63;
        float acc = b1[c];
        for (int k = 0; k < 64; ++k) acc += g[gi][k] * wT[k][c];
        h[gi][c] = fmaxf(acc, 0.f);
    }
    __syncthreads();
    for (int idx = t; idx < 64 * NCLASSES; idx += 256) {
        int gi = idx >> 4, c = idx & 15;
        float acc = b2[c];
        for (int k = 0; k < 64; ++k) acc += h[gi][k] * w2[c * 64 + k];
        out[gi * NCLASSES + c] = acc;
    }
}

// ---------------------------------------------------------------------------
extern "C" void kernel_launch(void* const* d_in, const int* in_sizes, int n_in,
                              void* d_out, int out_size, void* d_ws, size_t ws_size,
                              hipStream_t stream) {
    const float* x      = (const float*)d_in[0];
    const int*   ei     = (const int*)d_in[1];
    const int*   batch  = (const int*)d_in[2];
    const float* pre_w  = (const float*)d_in[3];
    const float* pre_b  = (const float*)d_in[4];
    const float* post_w = (const float*)d_in[5];
    const float* post_b = (const float*)d_in[6];
    const float* lin_w  = (const float*)d_in[7];
    const float* lin_b  = (const float*)d_in[8];
    const float* mlp_w1 = (const float*)d_in[9];
    const float* mlp_b1 = (const float*)d_in[10];
    const float* mlp_w2 = (const float*)d_in[11];
    const float* mlp_b2 = (const float*)d_in[12];

    const int* src = ei;
    const int* dst = ei + N_EDGES;

    char* base = (char*)d_ws;
    size_t off = 0;
    auto alloc = [&](size_t bytes) -> void* {
        void* ptr = base + off;
        off += (bytes + 255) & ~(size_t)255;
        return ptr;
    };
    int*   cnt       = (int*)alloc(N_NODES * 4);
    int*   row_start = (int*)alloc((N_NODES + 1) * 4);
    int*   rank      = (int*)alloc(N_EDGES * 4);
    int*   csr_src   = (int*)alloc(N_EDGES * 4);
    int*   bsum      = (int*)alloc(64 * 4);
    int*   boff      = (int*)alloc(64 * 4);
    float* logsum    = (float*)alloc(16);
    float* inv_deg   = (float*)alloc(N_NODES * 4);
    float* ampv      = (float*)alloc(N_NODES * 4);
    float* attv      = (float*)alloc(N_NODES * 4);
    float* p         = (float*)alloc((size_t)N_NODES * 64 * 4);
    float* q         = (float*)alloc((size_t)N_NODES * 64 * 4);
    float* aggr      = (float*)alloc((size_t)N_NODES * 256 * 4);
    float* xb0       = (float*)alloc((size_t)N_NODES * 64 * 4);
    float* xb1       = (float*)alloc((size_t)N_NODES * 64 * 4);
    float* g_sum     = (float*)alloc(64 * 64 * 4);
    int*   g_cnt     = (int*)alloc(64 * 4);
    u16*   WkS       = (u16*)alloc((size_t)3 * WKS_LAYER * 2);
    float* bcv       = (float*)alloc(3 * 64 * 4);

    // weight folding (pre-split bf16, frag-ordered, K-permuted) + zero-init
    k_comb<<<625, 256, 0, stream>>>(post_w, lin_w, post_b, lin_b, WkS, bcv,
                                    cnt, logsum);

    k_count<<<(N_EDGES + 255) / 256, 256, 0, stream>>>(dst, cnt, rank);
    k_chunk_sums<<<NCHUNKS, 256, 0, stream>>>(cnt, bsum, logsum);
    k_scan_top<<<1, 64, 0, stream>>>(bsum, boff, row_start);
    k_scan_chunks<<<NCHUNKS, 256, 0, stream>>>(cnt, boff, row_start);
    k_scatter<<<(N_EDGES + 255) / 256, 256, 0, stream>>>(src, dst, rank,
                                                         row_start, csr_src);
    k_scal<<<(N_NODES + 255) / 256, 256, 0, stream>>>(cnt, logsum, inv_deg,
                                                      ampv, attv, g_sum, g_cnt);

    const int GEMM_BLOCKS = (N_NODES + 63) / 64;   // 782
    const float* xin = x;
    float* bufs[3] = {xb0, xb1, xb0};
    for (int l = 0; l < NLAYERS; ++l) {
        k_pre<<<GEMM_BLOCKS, 256, 0, stream>>>(xin, pre_w + (size_t)l * 64 * 128,
                                               pre_b + l * 64, p, q);
        k_aggr<<<(N_NODES + 3) / 4, 256, 0, stream>>>(p, q, row_start, csr_src,
                                                      inv_deg, aggr);
        float* xo = bufs[l];
        k_post<<<GEMM_BLOCKS, 256, 0, stream>>>(xin, aggr, ampv, attv,
                                                WkS + (size_t)l * WKS_LAYER,
                                                bcv + l * 64, xo);
        xin = xo;
    }

    int pool_waves = (N_NODES + 15) / 16;
    k_pool<<<(pool_waves + 3) / 4, 256, 0, stream>>>(xin, batch, g_sum, g_cnt);
    k_mlp<<<1, 256, 0, stream>>>(g_sum, g_cnt, mlp_w1, mlp_b1, mlp_w2, mlp_b2,
                                 (float*)d_out);
}

// Round 12
// 469.782 us; speedup vs baseline: 1.5282x; 1.0463x over previous
//
#include <hip/hip_runtime.h>
#include <math.h>

#define N_NODES   50000
#define N_EDGES   800000
#define NUM_GRAPHS 64
#define FDIM      64
#define HDIM      64
#define NLAYERS   3
#define NCLASSES  16
#define EPS       1e-5f

#define SCAN_CHUNK 1024
#define NCHUNKS ((N_NODES + SCAN_CHUNK - 1) / SCAN_CHUNK)   // 49

typedef unsigned short u16;
typedef unsigned int   u32;
typedef __attribute__((ext_vector_type(8))) short short8;   // 8 bf16 (4 VGPRs)
typedef __attribute__((ext_vector_type(4))) float floatx4;  // MFMA accum

// WkS layout per layer (u16 bf16 bits):
//   [26 kchunk][3 split][4 ntile][16 n][32 k-swizzled] -> 159744 u16 per layer
// K-order: chunks 0-1 = x cols 0..63; then for aggr group j (j=0..7, 32 cols):
//   chunk 2+3j+0 = plain, +1 = amp, +2 = att.
// k position within a chunk row is swizzled: element (n16, kin=qh*8+jj) stored
// at n16*32 + ((qh + (n16>>1)) & 3)*8 + jj   (2-way LDS bank spread on read).
#define WKS_LAYER 159744
// PreS layout per layer: [2 kchunk][3 split][8 ntile][16 n][32 k-swizzled]
//   chunk stride = 12288 u16; split stride = 4096 u16 within chunk.
// B columns c128 in [0,128): c128<64 -> p col (Wi), c128>=64 -> q col (Wj).
#define PRES_LAYER 24576

// ---------------------------------------------------------------------------
__device__ inline void split1(float f, u16& h, u16& m, u16& l) {
    u32 b  = __float_as_uint(f);
    u32 hb = b & 0xFFFF0000u;
    float r = f - __uint_as_float(hb);
    u32 mb = __float_as_uint(r) & 0xFFFF0000u;
    float r2 = r - __uint_as_float(mb);
    u32 lb = __float_as_uint(r2) & 0xFFFF0000u;
    h = (u16)(hb >> 16); m = (u16)(mb >> 16); l = (u16)(lb >> 16);
}

// async global->LDS DMA, 16B per lane (dest = wave-uniform base + lane*16)
__device__ inline void gl_lds16(const void* g, void* l) {
    __builtin_amdgcn_global_load_lds(
        (const __attribute__((address_space(1))) u32*)g,
        (__attribute__((address_space(3))) u32*)l, 16, 0, 0);
}

// ---------------------------------------------------------------------------
// Weight folding Wk = (lin_w @ post_w) -> 3-way bf16 split (K-permuted,
// swizzled); PreS = pre_w 3-way bf16 split (same tile format, 8 ntiles);
// bc = lin_b + lin_w@post_b; zero-inits cnt/logsum.
__global__ __launch_bounds__(256) void k_comb(const float* __restrict__ post_w,
                                              const float* __restrict__ lin_w,
                                              const float* __restrict__ pre_w,
                                              const float* __restrict__ post_b,
                                              const float* __restrict__ lin_b,
                                              u16* __restrict__ WkS,
                                              u16* __restrict__ PreS,
                                              float* __restrict__ bcv,
                                              int* __restrict__ cnt,
                                              float* __restrict__ logsum) {
    int b = blockIdx.x, t = threadIdx.x;
    int zi = b * 256 + t;
    if (zi < N_NODES) cnt[zi] = 0;
    if (zi == 0) *logsum = 0.f;

    if (b < 624) {
        int c  = t & 63;
        int kl = t >> 6;
        int l  = b / 208;
        int o  = (b % 208) * 4 + kl;          // original K column in [0,832)
        const float* lw = lin_w + (size_t)l * 4096 + c * 64;
        const float* pw = post_w + (size_t)l * 53248 + o;
        float acc = 0.f;
        #pragma unroll 8
        for (int j = 0; j < 64; ++j)
            acc += lw[j] * pw[(size_t)j * 832];
        u16 h, m, lo;
        split1(acc, h, m, lo);

        // K permutation: o -> kn
        int kn;
        if (o < 64) kn = o;
        else {
            int s  = (o - 64) >> 8;           // 0 plain, 1 amp, 2 att
            int mm = (o - 64) & 255;          // aggr element index
            int j  = mm >> 5, r = mm & 31;
            kn = 64 + j * 96 + s * 32 + r;
        }
        int ch  = kn >> 5;
        int kin = kn & 31;
        int n16 = c & 15, nt = c >> 4;
        int swk = (((kin >> 3) + (n16 >> 1)) & 3) * 8 + (kin & 7);
        size_t base = (size_t)l * WKS_LAYER + (size_t)ch * 6144
                    + nt * 512 + n16 * 32 + swk;
        WkS[base]        = h;
        WkS[base + 2048] = m;
        WkS[base + 4096] = lo;
    } else if (b == 624) {
        if (t < 192) {
            int l = t >> 6, c = t & 63;
            float acc = lin_b[l * 64 + c];
            for (int j = 0; j < 64; ++j)
                acc += lin_w[(size_t)l * 4096 + c * 64 + j] * post_b[l * 64 + j];
            bcv[l * 64 + c] = acc;
        }
    } else {
        // PreS split: i indexes (l, c128, k); 96 blocks * 256 = 24576 elems
        int i = (b - 625) * 256 + t;
        int l = i >> 13;                      // /8192
        int rem = i & 8191;
        int c128 = rem >> 6;
        int k = rem & 63;
        float v;
        if (c128 < 64) v = pre_w[(size_t)l * 8192 + c128 * 128 + k];
        else           v = pre_w[(size_t)l * 8192 + (c128 - 64) * 128 + 64 + k];
        u16 h, m, lo;
        split1(v, h, m, lo);
        int ch = k >> 5, kin = k & 31;
        int nt = c128 >> 4, n16 = c128 & 15;
        int swk = (((kin >> 3) + (n16 >> 1)) & 3) * 8 + (kin & 7);
        size_t base = (size_t)l * PRES_LAYER + (size_t)ch * 12288
                    + nt * 512 + n16 * 32 + swk;
        PreS[base]        = h;
        PreS[base + 4096] = m;
        PreS[base + 8192] = lo;
    }
}

// ---------------------------------------------------------------------------
// CSR build: degree histogram + per-edge rank (arrival index within its dst)
__global__ void k_count(const int* __restrict__ dst, int* __restrict__ cnt,
                        int* __restrict__ rank) {
    int e = blockIdx.x * 256 + threadIdx.x;
    if (e < N_EDGES) rank[e] = atomicAdd(&cnt[dst[e]], 1);
}

__global__ void k_chunk_sums(const int* __restrict__ cnt, int* __restrict__ bsum,
                             float* __restrict__ logsum) {
    __shared__ int   ired[256];
    __shared__ float lred[256];
    int b = blockIdx.x, t = threadIdx.x;
    int base = b * SCAN_CHUNK;
    int s = 0; float ls = 0.f;
    for (int i = t; i < SCAN_CHUNK; i += 256) {
        int idx = base + i;
        if (idx < N_NODES) {
            int v = cnt[idx];
            s += v;
            ls += logf((float)v + 1.0f);
        }
    }
    ired[t] = s; lred[t] = ls;
    __syncthreads();
    for (int off = 128; off > 0; off >>= 1) {
        if (t < off) { ired[t] += ired[t + off]; lred[t] += lred[t + off]; }
        __syncthreads();
    }
    if (t == 0) { bsum[b] = ired[0]; atomicAdd(logsum, lred[0]); }
}

__global__ void k_scan_top(const int* __restrict__ bsum, int* __restrict__ boff,
                           int* __restrict__ row_start) {
    if (threadIdx.x == 0) {
        int acc = 0;
        for (int i = 0; i < NCHUNKS; ++i) { boff[i] = acc; acc += bsum[i]; }
        row_start[N_NODES] = acc;
    }
}

__global__ void k_scan_chunks(const int* __restrict__ cnt, const int* __restrict__ boff,
                              int* __restrict__ row_start) {
    __shared__ int tsum[256];
    int b = blockIdx.x, t = threadIdx.x;
    int base = b * SCAN_CHUNK + t * 4;
    int v[4]; int s = 0;
    #pragma unroll
    for (int i = 0; i < 4; ++i) {
        int idx = base + i;
        v[i] = (idx < N_NODES) ? cnt[idx] : 0;
        s += v[i];
    }
    tsum[t] = s;
    __syncthreads();
    for (int off = 1; off < 256; off <<= 1) {
        int val = (t >= off) ? tsum[t - off] : 0;
        __syncthreads();
        tsum[t] += val;
        __syncthreads();
    }
    int excl = boff[b] + tsum[t] - s;
    #pragma unroll
    for (int i = 0; i < 4; ++i) {
        int idx = base + i;
        if (idx < N_NODES) row_start[idx] = excl;
        excl += v[i];
    }
}

// atomic-free scatter: slot = row_start[dst] + rank (plain writes, L2-coalesced)
__global__ void k_scatter(const int* __restrict__ src, const int* __restrict__ dst,
                          const int* __restrict__ rank,
                          const int* __restrict__ row_start,
                          int* __restrict__ csr_src) {
    int e = blockIdx.x * 256 + threadIdx.x;
    if (e < N_EDGES) {
        int d = dst[e];
        csr_src[row_start[d] + rank[e]] = src[e];
    }
}

// per-node degree scalers; block 0 also zero-inits pooling accumulators
__global__ void k_scal(const int* __restrict__ cnt, const float* __restrict__ logsum,
                       float* __restrict__ inv_deg, float* __restrict__ ampv,
                       float* __restrict__ attv, float* __restrict__ g_sum,
                       int* __restrict__ g_cnt) {
    int n = blockIdx.x * 256 + threadIdx.x;
    if (blockIdx.x == 0) {
        for (int i = threadIdx.x; i < 4096; i += 256) g_sum[i] = 0.f;
        if (threadIdx.x < 64) g_cnt[threadIdx.x] = 0;
    }
    if (n < N_NODES) {
        float avg = logsum[0] / (float)N_NODES;
        float degf = fmaxf((float)cnt[n], 1.0f);
        inv_deg[n] = 1.0f / degf;
        float ld = logf(degf + 1.0f);
        ampv[n] = ld / avg;
        attv[n] = avg / ld;
    }
}

// ---------------------------------------------------------------------------
// MFMA k_pre: [p|q] = x @ [Wi|Wj]^T (+pre_b on p), exact 3-way bf16 split.
// Weights pre-split frag-ordered (PreS); single staging (2 chunks, 48KB LDS),
// one barrier, 96 MFMAs/wave, no fp32 LDS round-trip.
__global__ __launch_bounds__(256, 4) void k_pre(const float* __restrict__ x,
                                                const u16* __restrict__ PreS,
                                                const float* __restrict__ pre_b,
                                                float* __restrict__ p,
                                                float* __restrict__ q) {
    __shared__ u16 ldsB[2 * 12288];
    int t = threadIdx.x;
    int w = t >> 6;
    int lane = t & 63;
    int m = lane & 15;
    int qh = lane >> 4;
    int rowBase = blockIdx.x * 64;

    int myrow = rowBase + 16 * w + m;
    bool vr = myrow < N_NODES;
    int crow = vr ? myrow : 0;
    const float* xrow = x + (size_t)crow * 64;

    int bo = m * 32 + ((qh + (m >> 1)) & 3) * 8;

    // stage both K-chunks: per wave per chunk 6144B = 6 x (64 lanes x 16B)
    #pragma unroll
    for (int ch = 0; ch < 2; ++ch) {
        const char* g = (const char*)PreS + (size_t)ch * 24576 + w * 6144 + lane * 16;
        char* l = (char*)ldsB + ch * 24576 + w * 6144;
        #pragma unroll
        for (int i = 0; i < 6; ++i)
            gl_lds16(g + i * 1024, l + i * 1024);
    }
    // A: both 32-col chunks of this lane's row (unconditional, clamped row)
    float fa[2][8];
    #pragma unroll
    for (int ch = 0; ch < 2; ++ch) {
        const float* sp = xrow + ch * 32 + qh * 8;
        float4 u0 = *(const float4*)sp;
        float4 u1 = *(const float4*)(sp + 4);
        fa[ch][0] = vr ? u0.x : 0.f; fa[ch][1] = vr ? u0.y : 0.f;
        fa[ch][2] = vr ? u0.z : 0.f; fa[ch][3] = vr ? u0.w : 0.f;
        fa[ch][4] = vr ? u1.x : 0.f; fa[ch][5] = vr ? u1.y : 0.f;
        fa[ch][6] = vr ? u1.z : 0.f; fa[ch][7] = vr ? u1.w : 0.f;
    }
    asm volatile("s_waitcnt vmcnt(0)" ::: "memory");
    __syncthreads();

    floatx4 acc[8] = {};
    #pragma unroll
    for (int ch = 0; ch < 2; ++ch) {
        union { u32 u[4]; short8 s8; } AH, AM, AL;
        #pragma unroll
        for (int i = 0; i < 4; ++i) {
            float f0 = fa[ch][2 * i], f1 = fa[ch][2 * i + 1];
            u32 b0 = __float_as_uint(f0), b1 = __float_as_uint(f1);
            u32 h0 = b0 & 0xFFFF0000u,  h1 = b1 & 0xFFFF0000u;
            float r0 = f0 - __uint_as_float(h0);
            float r1 = f1 - __uint_as_float(h1);
            u32 m0 = __float_as_uint(r0) & 0xFFFF0000u;
            u32 m1 = __float_as_uint(r1) & 0xFFFF0000u;
            float s0 = r0 - __uint_as_float(m0);
            float s1 = r1 - __uint_as_float(m1);
            u32 l0 = __float_as_uint(s0) & 0xFFFF0000u;
            u32 l1 = __float_as_uint(s1) & 0xFFFF0000u;
            AH.u[i] = (h0 >> 16) | h1;
            AM.u[i] = (m0 >> 16) | m1;
            AL.u[i] = (l0 >> 16) | l1;
        }
        const u16* Bb = ldsB + ch * 12288;
        #pragma unroll
        for (int nt = 0; nt < 8; ++nt) {
            short8 bH = *(const short8*)(Bb + nt * 512 + bo);
            short8 bM = *(const short8*)(Bb + 4096 + nt * 512 + bo);
            short8 bL = *(const short8*)(Bb + 8192 + nt * 512 + bo);
            acc[nt] = __builtin_amdgcn_mfma_f32_16x16x32_bf16(AH.s8, bH, acc[nt], 0, 0, 0);
            acc[nt] = __builtin_amdgcn_mfma_f32_16x16x32_bf16(AH.s8, bM, acc[nt], 0, 0, 0);
            acc[nt] = __builtin_amdgcn_mfma_f32_16x16x32_bf16(AM.s8, bH, acc[nt], 0, 0, 0);
            acc[nt] = __builtin_amdgcn_mfma_f32_16x16x32_bf16(AH.s8, bL, acc[nt], 0, 0, 0);
            acc[nt] = __builtin_amdgcn_mfma_f32_16x16x32_bf16(AM.s8, bM, acc[nt], 0, 0, 0);
            acc[nt] = __builtin_amdgcn_mfma_f32_16x16x32_bf16(AL.s8, bH, acc[nt], 0, 0, 0);
        }
    }

    // epilogue: C/D layout col = lane&15, row = (lane>>4)*4 + reg
    int col = m;
    #pragma unroll
    for (int nt = 0; nt < 8; ++nt) {
        int cbase = (nt & 3) * 16 + col;
        float bias = (nt < 4) ? pre_b[cbase] : 0.f;
        float* outp = (nt < 4) ? p : q;
        #pragma unroll
        for (int reg = 0; reg < 4; ++reg) {
            int grow = rowBase + 16 * w + qh * 4 + reg;
            if (grow < N_NODES)
                outp[(size_t)grow * 64 + cbase] = acc[nt][reg] + bias;
        }
    }
}

// ---------------------------------------------------------------------------
// Aggregation (unchanged, passing r6 version)
__global__ __launch_bounds__(256) void k_aggr(const float* __restrict__ p,
                                              const float* __restrict__ q,
                                              const int* __restrict__ row_start,
                                              const int* __restrict__ csr_src,
                                              const float* __restrict__ inv_deg,
                                              float* __restrict__ aggr) {
    int wid  = (blockIdx.x * 256 + threadIdx.x) >> 6;
    int lane = threadIdx.x & 63;
    if (wid >= N_NODES) return;
    int n = wid;
    int beg = row_start[n], end = row_start[n + 1];
    float sum = 0.f, sq = 0.f;
    float mn = INFINITY, mx = -INFINITY;
    int e = beg;
    for (; e + 7 < end; e += 8) {
        float qv[8];
        #pragma unroll
        for (int u = 0; u < 8; ++u) {
            int s = csr_src[e + u];
            qv[u] = q[(size_t)s * 64 + lane];
        }
        #pragma unroll
        for (int u = 0; u < 8; ++u) {
            float m = qv[u];
            sum += m; sq += m * m;
            mn = fminf(mn, m); mx = fmaxf(mx, m);
        }
    }
    for (; e + 3 < end; e += 4) {
        float qv[4];
        #pragma unroll
        for (int u = 0; u < 4; ++u) {
            int s = csr_src[e + u];
            qv[u] = q[(size_t)s * 64 + lane];
        }
        #pragma unroll
        for (int u = 0; u < 4; ++u) {
            float m = qv[u];
            sum += m; sq += m * m;
            mn = fminf(mn, m); mx = fmaxf(mx, m);
        }
    }
    for (; e < end; ++e) {
        int s = csr_src[e];
        float m = q[(size_t)s * 64 + lane];
        sum += m; sq += m * m;
        mn = fminf(mn, m); mx = fmaxf(mx, m);
    }
    float* a = aggr + (size_t)n * 256;
    if (end <= beg) {
        a[lane]       = 0.f;
        a[64 + lane]  = 0.f;
        a[128 + lane] = 0.f;
        a[192 + lane] = sqrtf(EPS);
    } else {
        float pv = p[n * 64 + lane];
        float id = inv_deg[n];
        float meanq = sum * id;
        float var = fmaxf(sq * id - meanq * meanq, 0.f);
        a[lane]       = pv + meanq;
        a[64 + lane]  = pv + mn;
        a[128 + lane] = pv + mx;
        a[192 + lane] = sqrtf(var + EPS);
    }
}

// ---------------------------------------------------------------------------
// MFMA k_post v4 (unchanged, passing r11 version): triple-buffered async DMA
// with fine-grained vmcnt(5) + raw s_barrier; 6-MFMA exact 3-way bf16 split.
__global__ __launch_bounds__(256, 4) void k_post(const float* __restrict__ x,
                                                 const float* __restrict__ aggr,
                                                 const float* __restrict__ ampv,
                                                 const float* __restrict__ attv,
                                                 const u16* __restrict__ WkS,
                                                 const float* __restrict__ bc,
                                                 float* __restrict__ xout) {
    __shared__ u16 ldsB[3 * 6144];
    int t = threadIdx.x;
    int w = t >> 6;
    int lane = t & 63;
    int m = lane & 15;
    int qh = lane >> 4;
    int rowBase = blockIdx.x * 64;

    int myrow = rowBase + 16 * w + m;
    bool vr = myrow < N_NODES;
    int crow = vr ? myrow : 0;
    float ampR = vr ? ampv[crow] : 0.f;
    float attR = vr ? attv[crow] : 0.f;
    const float* xrow = x + (size_t)crow * 64;
    const float* arow = aggr + (size_t)crow * 256;

    int bo = m * 32 + ((qh + (m >> 1)) & 3) * 8;

    floatx4 acc[4] = {};
    float fc[8], fn[8];

    auto aptr = [&](int ch) -> const float* {
        if (ch <= 0) return xrow;
        if (ch == 1) return xrow + 32;
        int j = (ch - 2) / 3;
        if (j > 7) j = 7;
        return arow + j * 32;
    };
    auto loadRaw = [&](const float* sp, float* f) {
        float4 u0 = *(const float4*)(sp + qh * 8);
        float4 u1 = *(const float4*)(sp + qh * 8 + 4);
        f[0] = vr ? u0.x : 0.f; f[1] = vr ? u0.y : 0.f;
        f[2] = vr ? u0.z : 0.f; f[3] = vr ? u0.w : 0.f;
        f[4] = vr ? u1.x : 0.f; f[5] = vr ? u1.y : 0.f;
        f[6] = vr ? u1.z : 0.f; f[7] = vr ? u1.w : 0.f;
    };
    auto stageIssue = [&](int ch, int buf) {
        const char* g = (const char*)WkS + (size_t)ch * 12288 + w * 3072 + lane * 16;
        char* l = (char*)ldsB + buf * 12288 + w * 3072;
        #pragma unroll
        for (int i = 0; i < 3; ++i)
            gl_lds16(g + i * 1024, l + i * 1024);
    };

    loadRaw(aptr(0), fc);
    stageIssue(0, 0);
    stageIssue(1, 1);
    asm volatile("s_waitcnt vmcnt(3)" ::: "memory");
    asm volatile("s_barrier" ::: "memory");

    for (int ch = 0; ch < 26; ++ch) {
        loadRaw(aptr(ch + 1), fn);
        int ch2 = (ch + 2 < 26) ? ch + 2 : ch + 2 - 26;
        stageIssue(ch2, (ch + 2) % 3);

        float sc = 1.f;
        if (ch >= 2) {
            int s = (ch - 2) % 3;
            sc = (s == 0) ? 1.f : ((s == 1) ? ampR : attR);
        }

        union { u32 u[4]; short8 s8; } AH, AM, AL;
        #pragma unroll
        for (int i = 0; i < 4; ++i) {
            float f0 = fc[2 * i] * sc, f1 = fc[2 * i + 1] * sc;
            u32 b0 = __float_as_uint(f0), b1 = __float_as_uint(f1);
            u32 h0 = b0 & 0xFFFF0000u,  h1 = b1 & 0xFFFF0000u;
            float r0 = f0 - __uint_as_float(h0);
            float r1 = f1 - __uint_as_float(h1);
            u32 m0 = __float_as_uint(r0) & 0xFFFF0000u;
            u32 m1 = __float_as_uint(r1) & 0xFFFF0000u;
            float s0 = r0 - __uint_as_float(m0);
            float s1 = r1 - __uint_as_float(m1);
            u32 l0 = __float_as_uint(s0) & 0xFFFF0000u;
            u32 l1 = __float_as_uint(s1) & 0xFFFF0000u;
            AH.u[i] = (h0 >> 16) | h1;
            AM.u[i] = (m0 >> 16) | m1;
            AL.u[i] = (l0 >> 16) | l1;
        }

        const u16* Bb = ldsB + (ch % 3) * 6144;
        #pragma unroll
        for (int nt = 0; nt < 4; ++nt) {
            short8 bH = *(const short8*)(Bb + nt * 512 + bo);
            short8 bM = *(const short8*)(Bb + 2048 + nt * 512 + bo);
            short8 bL = *(const short8*)(Bb + 4096 + nt * 512 + bo);
            acc[nt] = __builtin_amdgcn_mfma_f32_16x16x32_bf16(AH.s8, bH, acc[nt], 0, 0, 0);
            acc[nt] = __builtin_amdgcn_mfma_f32_16x16x32_bf16(AH.s8, bM, acc[nt], 0, 0, 0);
            acc[nt] = __builtin_amdgcn_mfma_f32_16x16x32_bf16(AM.s8, bH, acc[nt], 0, 0, 0);
            acc[nt] = __builtin_amdgcn_mfma_f32_16x16x32_bf16(AH.s8, bL, acc[nt], 0, 0, 0);
            acc[nt] = __builtin_amdgcn_mfma_f32_16x16x32_bf16(AM.s8, bM, acc[nt], 0, 0, 0);
            acc[nt] = __builtin_amdgcn_mfma_f32_16x16x32_bf16(AL.s8, bH, acc[nt], 0, 0, 0);
        }

        asm volatile("s_waitcnt vmcnt(5)" ::: "memory");
        asm volatile("s_barrier" ::: "memory");

        #pragma unroll
        for (int i = 0; i < 8; ++i) fc[i] = fn[i];
    }

    int col = lane & 15;
    #pragma unroll
    for (int nt = 0; nt < 4; ++nt) {
        float bias = bc[nt * 16 + col];
        #pragma unroll
        for (int reg = 0; reg < 4; ++reg) {
            int grow = rowBase + 16 * w + qh * 4 + reg;
            if (grow < N_NODES) {
                xout[(size_t)grow * 64 + nt * 16 + col] =
                    fmaxf(acc[nt][reg] + bias, 0.f);
            }
        }
    }
}

// ---------------------------------------------------------------------------
// Mean pooling: 16 nodes per wave (3125 waves) -> latency hidden by TLP.
__global__ __launch_bounds__(256) void k_pool(const float* __restrict__ x,
                                              const int* __restrict__ batch,
                                              float* __restrict__ g_sum,
                                              int* __restrict__ g_cnt) {
    int lane = threadIdx.x & 63;
    int wave = blockIdx.x * 4 + (threadIdx.x >> 6);
    const int NPW = 16;
    int beg = wave * NPW;
    if (beg >= N_NODES) return;
    int end = min(beg + NPW, N_NODES);
    float acc = 0.f;
    int cur = batch[beg];
    int c = 0;
    for (int n = beg; n < end; ++n) {
        int b = batch[n];
        if (b != cur) {
            atomicAdd(&g_sum[cur * 64 + lane], acc);
            if (lane == 0) atomicAdd(&g_cnt[cur], c);
            acc = 0.f; c = 0; cur = b;
        }
        acc += x[n * 64 + lane];
        ++c;
    }
    atomicAdd(&g_sum[cur * 64 + lane], acc);
    if (lane == 0) atomicAdd(&g_cnt[cur], c);
}

__global__ __launch_bounds__(256) void k_mlp(const float* __restrict__ g_sum,
                                             const int* __restrict__ g_cnt,
                                             const float* __restrict__ w1,
                                             const float* __restrict__ b1,
                                             const float* __restrict__ w2,
                                             const float* __restrict__ b2,
                                             float* __restrict__ out) {
    __shared__ float g[64][64];
    __shared__ float h[64][64];
    __shared__ float wT[64][65];
    int t = threadIdx.x;
    for (int idx = t; idx < 4096; idx += 256) {
        int gi = idx >> 6, c = idx & 63;
        float cntf = fmaxf((float)g_cnt[gi], 1.f);
        g[gi][c] = g_sum[idx] / cntf;
    }
    for (int idx = t; idx < 4096; idx += 256) {
        int c = idx >> 6, k = idx & 63;
        wT[k][c] = w1[c * 64 + k];
    }
    __syncthreads();
    for (int idx = t; idx < 4096; idx += 256) {
        int gi = idx >> 6, c = idx & 63;
        float acc = b1[c];
        for (int k = 0; k < 64; ++k) acc += g[gi][k] * wT[k][c];
        h[gi][c] = fmaxf(acc, 0.f);
    }
    __syncthreads();
    for (int idx = t; idx < 64 * NCLASSES; idx += 256) {
        int gi = idx >> 4, c = idx & 15;
        float acc = b2[c];
        for (int k = 0; k < 64; ++k) acc += h[gi][k] * w2[c * 64 + k];
        out[gi * NCLASSES + c] = acc;
    }
}

// ---------------------------------------------------------------------------
extern "C" void kernel_launch(void* const* d_in, const int* in_sizes, int n_in,
                              void* d_out, int out_size, void* d_ws, size_t ws_size,
                              hipStream_t stream) {
    const float* x      = (const float*)d_in[0];
    const int*   ei     = (const int*)d_in[1];
    const int*   batch  = (const int*)d_in[2];
    const float* pre_w  = (const float*)d_in[3];
    const float* pre_b  = (const float*)d_in[4];
    const float* post_w = (const float*)d_in[5];
    const float* post_b = (const float*)d_in[6];
    const float* lin_w  = (const float*)d_in[7];
    const float* lin_b  = (const float*)d_in[8];
    const float* mlp_w1 = (const float*)d_in[9];
    const float* mlp_b1 = (const float*)d_in[10];
    const float* mlp_w2 = (const float*)d_in[11];
    const float* mlp_b2 = (const float*)d_in[12];

    const int* src = ei;
    const int* dst = ei + N_EDGES;

    char* base = (char*)d_ws;
    size_t off = 0;
    auto alloc = [&](size_t bytes) -> void* {
        void* ptr = base + off;
        off += (bytes + 255) & ~(size_t)255;
        return ptr;
    };
    int*   cnt       = (int*)alloc(N_NODES * 4);
    int*   row_start = (int*)alloc((N_NODES + 1) * 4);
    int*   rank      = (int*)alloc(N_EDGES * 4);
    int*   csr_src   = (int*)alloc(N_EDGES * 4);
    int*   bsum      = (int*)alloc(64 * 4);
    int*   boff      = (int*)alloc(64 * 4);
    float* logsum    = (float*)alloc(16);
    float* inv_deg   = (float*)alloc(N_NODES * 4);
    float* ampv      = (float*)alloc(N_NODES * 4);
    float* attv      = (float*)alloc(N_NODES * 4);
    float* p         = (float*)alloc((size_t)N_NODES * 64 * 4);
    float* q         = (float*)alloc((size_t)N_NODES * 64 * 4);
    float* aggr      = (float*)alloc((size_t)N_NODES * 256 * 4);
    float* xb0       = (float*)alloc((size_t)N_NODES * 64 * 4);
    float* xb1       = (float*)alloc((size_t)N_NODES * 64 * 4);
    float* g_sum     = (float*)alloc(64 * 64 * 4);
    int*   g_cnt     = (int*)alloc(64 * 4);
    u16*   WkS       = (u16*)alloc((size_t)3 * WKS_LAYER * 2);
    u16*   PreS      = (u16*)alloc((size_t)3 * PRES_LAYER * 2);
    float* bcv       = (float*)alloc(3 * 64 * 4);

    // weight folding + pre_w split + workspace zero-init
    k_comb<<<721, 256, 0, stream>>>(post_w, lin_w, pre_w, post_b, lin_b,
                                    WkS, PreS, bcv, cnt, logsum);

    k_count<<<(N_EDGES + 255) / 256, 256, 0, stream>>>(dst, cnt, rank);
    k_chunk_sums<<<NCHUNKS, 256, 0, stream>>>(cnt, bsum, logsum);
    k_scan_top<<<1, 64, 0, stream>>>(bsum, boff, row_start);
    k_scan_chunks<<<NCHUNKS, 256, 0, stream>>>(cnt, boff, row_start);
    k_scatter<<<(N_EDGES + 255) / 256, 256, 0, stream>>>(src, dst, rank,
                                                         row_start, csr_src);
    k_scal<<<(N_NODES + 255) / 256, 256, 0, stream>>>(cnt, logsum, inv_deg,
                                                      ampv, attv, g_sum, g_cnt);

    const int GEMM_BLOCKS = (N_NODES + 63) / 64;   // 782
    const float* xin = x;
    float* bufs[3] = {xb0, xb1, xb0};
    for (int l = 0; l < NLAYERS; ++l) {
        k_pre<<<GEMM_BLOCKS, 256, 0, stream>>>(xin, PreS + (size_t)l * PRES_LAYER,
                                               pre_b + l * 64, p, q);
        k_aggr<<<(N_NODES + 3) / 4, 256, 0, stream>>>(p, q, row_start, csr_src,
                                                      inv_deg, aggr);
        float* xo = bufs[l];
        k_post<<<GEMM_BLOCKS, 256, 0, stream>>>(xin, aggr, ampv, attv,
                                                WkS + (size_t)l * WKS_LAYER,
                                                bcv + l * 64, xo);
        xin = xo;
    }

    int pool_waves = (N_NODES + 15) / 16;
    k_pool<<<(pool_waves + 3) / 4, 256, 0, stream>>>(xin, batch, g_sum, g_cnt);
    k_mlp<<<1, 256, 0, stream>>>(g_sum, g_cnt, mlp_w1, mlp_b1, mlp_w2, mlp_b2,
                                 (float*)d_out);
}